// Round 3
// baseline (20122.569 us; speedup 1.0000x reference)
//
#include <hip/hip_runtime.h>
#include <math.h>

// ---------------------------------------------------------------------------
// SDTP forward, round 3: pre-converted bf16x2 planes + clean bf16 MFMA GEMM.
// V=32000 D=2048 L=4 H=16 FF=8192 B=2 S=2048 DH=128, prune@{1,2} keep 50%.
// All transformer GEMMs: 3-phase stacked bf16x2 (Ah*Wh + Ah*Wl + Al*Wh),
// operands converted ONCE (fused into producer epilogues / weight-transpose
// kernels). lm_head: old in-kernel-convert 1-pass bf16. Attention exact fp32.
// Workspace layout (6R + misc, identical footprint to round 1/2):
//   [0..5R)  H0,H1,CQ,CK,CV  fp32
//   [5R..6R) A'D planes (AH,AL bf16 [4096][2048] each)
//   [6R..)   COS,SIN,SC,FLG,IDX,M0,M1
//   W' for wq..wo lives inside Nc (idle); MLP W' chunks alias CV; A'FF aliases CQ/CK.
// ---------------------------------------------------------------------------

#define DD 2048
#define HH 16
#define DHH 128
#define FFF 8192
#define BBATCH 2
#define SSEQ 2048
#define VV 32000
#define LLAYERS 4

typedef float4 f4;
typedef __attribute__((ext_vector_type(8))) short short8;    // 8 bf16 = 4 VGPR
typedef __attribute__((ext_vector_type(4))) float f32x4;
typedef unsigned short u16;

__device__ inline u16 bf16rne(float x) {
    unsigned u = __float_as_uint(x);
    unsigned r = (u + 0x7FFFu + ((u >> 16) & 1u)) >> 16;
    return (u16)r;
}
__device__ inline float bf16tof(u16 h) {
    return __uint_as_float(((unsigned)h) << 16);
}

// ---------------- embedding gather ----------------
__global__ void k_embed(const int* __restrict__ ids, const float* __restrict__ emb,
                        float* __restrict__ out) {
    int row = blockIdx.x;
    int id  = ids[row];
    const f4* src = (const f4*)(emb + (size_t)id * DD);
    f4*       dst = (f4*)(out + (size_t)row * DD);
    for (int i = threadIdx.x; i < DD / 4; i += blockDim.x) dst[i] = src[i];
}

__global__ void k_copy_int(const int* __restrict__ src, int* __restrict__ dst, int n) {
    int i = blockIdx.x * blockDim.x + threadIdx.x;
    if (i < n) dst[i] = src[i];
}

// ---------------- rmsnorm (fp32 out, for lnf) ----------------
__global__ __launch_bounds__(256) void k_rmsnorm(const float* __restrict__ x,
                                                 const float* __restrict__ w,
                                                 float* __restrict__ out) {
    int row = blockIdx.x;
    const float* xr = x + (size_t)row * DD;
    float ss = 0.f;
    for (int i = threadIdx.x; i < DD / 4; i += blockDim.x) {
        f4 v = ((const f4*)xr)[i];
        ss += v.x * v.x + v.y * v.y + v.z * v.z + v.w * v.w;
    }
    for (int o = 32; o > 0; o >>= 1) ss += __shfl_down(ss, o);
    __shared__ float red[4];
    int wid = threadIdx.x >> 6, lane = threadIdx.x & 63;
    if (lane == 0) red[wid] = ss;
    __syncthreads();
    float tot = red[0] + red[1] + red[2] + red[3];
    float inv = 1.0f / sqrtf(tot / (float)DD + 1e-6f);
    float* orow = out + (size_t)row * DD;
    for (int i = threadIdx.x; i < DD / 4; i += blockDim.x) {
        f4 v = ((const f4*)xr)[i];
        f4 wv = ((const f4*)w)[i];
        f4 o;
        o.x = v.x * wv.x * inv; o.y = v.y * wv.y * inv;
        o.z = v.z * wv.z * inv; o.w = v.w * wv.w * inv;
        ((f4*)orow)[i] = o;
    }
}

// ---------------- rmsnorm -> bf16 hi/lo planes ----------------
__global__ __launch_bounds__(256) void k_rmsnorm_cvt(const float* __restrict__ x,
                                                     const float* __restrict__ w,
                                                     u16* __restrict__ OH,
                                                     u16* __restrict__ OL) {
    int row = blockIdx.x;
    const float* xr = x + (size_t)row * DD;
    float ss = 0.f;
    for (int i = threadIdx.x; i < DD / 4; i += blockDim.x) {
        f4 v = ((const f4*)xr)[i];
        ss += v.x * v.x + v.y * v.y + v.z * v.z + v.w * v.w;
    }
    for (int o = 32; o > 0; o >>= 1) ss += __shfl_down(ss, o);
    __shared__ float red[4];
    int wid = threadIdx.x >> 6, lane = threadIdx.x & 63;
    if (lane == 0) red[wid] = ss;
    __syncthreads();
    float tot = red[0] + red[1] + red[2] + red[3];
    float inv = 1.0f / sqrtf(tot / (float)DD + 1e-6f);
    for (int i = threadIdx.x; i < DD / 4; i += blockDim.x) {
        f4 v = ((const f4*)xr)[i];
        f4 wv = ((const f4*)w)[i];
        float o[4];
        o[0] = v.x * wv.x * inv; o[1] = v.y * wv.y * inv;
        o[2] = v.z * wv.z * inv; o[3] = v.w * wv.w * inv;
        ushort4 hv, lv;
        u16* hp = (u16*)&hv; u16* lp = (u16*)&lv;
#pragma unroll
        for (int j = 0; j < 4; j++) {
            u16 h = bf16rne(o[j]);
            hp[j] = h;
            lp[j] = bf16rne(o[j] - bf16tof(h));
        }
        *(ushort4*)&OH[(size_t)row * DD + i * 4] = hv;
        *(ushort4*)&OL[(size_t)row * DD + i * 4] = lv;
    }
}

// ---------------- weight transpose+convert: W[K][N] -> Wt[n][2K] (hi|lo) ----
// grid (NCH/64, K/64); Wt row-major with leading dim 2K; chunk col offset nc0.
__global__ __launch_bounds__(256) void k_cvt_w(const float* __restrict__ W,
                                               u16* __restrict__ Wt,
                                               int K, int N, int nc0) {
    __shared__ float T[64][65];
    int tid = threadIdx.x;
    int n0g = nc0 + blockIdx.x * 64;
    int k0  = blockIdx.y * 64;
#pragma unroll
    for (int it = 0; it < 4; it++) {
        int r = it * 16 + (tid >> 4);
        int c4 = (tid & 15) * 4;
        f4 v = *(const f4*)(W + (size_t)(k0 + r) * N + n0g + c4);
        T[r][c4 + 0] = v.x; T[r][c4 + 1] = v.y;
        T[r][c4 + 2] = v.z; T[r][c4 + 3] = v.w;
    }
    __syncthreads();
    int nl = tid >> 2;             // 0..63
    int ks = (tid & 3) * 16;       // 0,16,32,48
    u16 hi[16], lo[16];
#pragma unroll
    for (int j = 0; j < 16; j++) {
        float v = T[ks + j][nl];
        u16 h = bf16rne(v);
        hi[j] = h;
        lo[j] = bf16rne(v - bf16tof(h));
    }
    size_t base = (size_t)(blockIdx.x * 64 + nl) * (2 * (size_t)K) + k0 + ks;
    *(short8*)&Wt[base]     = *(short8*)&hi[0];
    *(short8*)&Wt[base + 8] = *(short8*)&hi[8];
    *(short8*)&Wt[base + K]     = *(short8*)&lo[0];
    *(short8*)&Wt[base + K + 8] = *(short8*)&lo[8];
}

// ---------------- bf16 MFMA GEMM over stacked K'=3K ----------------
// A planes AH/AL [M][K] bf16; W [n][2K] bf16 (hi at k, lo at K+k).
// Phases: p0 Ah*Wh, p1 Ah*Wl, p2 Al*Wh. Block 128x128, BK=64, 4 waves (2x2).
// DUAL: two W's, epilogue silu(g)*u -> bf16 hi/lo planes OH/OL (ld = ldC).
__device__ inline void stage_tile(const u16* __restrict__ src, int ld,
                                  u16* __restrict__ lds, int tid) {
#pragma unroll
    for (int it = 0; it < 4; it++) {
        int row = it * 32 + (tid >> 3);
        int c   = tid & 7;
        int cs  = c ^ (row & 7);
        short8 v = *(const short8*)(src + (size_t)row * ld + c * 8);
        *(short8*)&lds[row * 64 + cs * 8] = v;
    }
}

template <int RES, int DUAL>
__global__ __launch_bounds__(256, 2) void k_bgemm(const u16* __restrict__ AH,
                                                  const u16* __restrict__ AL,
                                                  const u16* __restrict__ W1,
                                                  const u16* __restrict__ W2,
                                                  const float* __restrict__ Rsrc,
                                                  float* __restrict__ C,
                                                  u16* __restrict__ OH,
                                                  u16* __restrict__ OL,
                                                  int M, int ldC, int K) {
    constexpr int NW = DUAL ? 2 : 1;
    __shared__ u16 As[128 * 64];
    __shared__ u16 Bs[NW][128 * 64];
    int tid = threadIdx.x;
    int m0 = blockIdx.y * 128, n0 = blockIdx.x * 128;
    int lane = tid & 63, w = tid >> 6;
    int wm = w >> 1, wn = w & 1;
    int lr = lane & 15, lq = lane >> 4;

    f32x4 acc[NW][4][4];
#pragma unroll
    for (int u = 0; u < NW; u++)
#pragma unroll
        for (int i = 0; i < 4; i++)
#pragma unroll
            for (int j = 0; j < 4; j++)
#pragma unroll
                for (int r = 0; r < 4; r++) acc[u][i][j][r] = 0.f;

    const int KT = 3 * K;
    for (int kb = 0; kb < KT; kb += 64) {
        int p  = (kb >= 2 * K) ? 2 : ((kb >= K) ? 1 : 0);
        int ks = kb - p * K;
        const u16* Ap = ((p == 2) ? AL : AH) + (size_t)m0 * K + ks;
        size_t boff = (size_t)n0 * 2 * (size_t)K + ((p == 1) ? K : 0) + ks;
        __syncthreads();
        stage_tile(Ap, K, As, tid);
        stage_tile(W1 + boff, 2 * K, Bs[0], tid);
        if constexpr (DUAL) stage_tile(W2 + boff, 2 * K, Bs[1], tid);
        __syncthreads();
#pragma unroll
        for (int kk = 0; kk < 2; kk++) {
            short8 a[4];
#pragma unroll
            for (int i = 0; i < 4; i++) {
                int row = wm * 64 + i * 16 + lr;
                int cs = (kk * 4 + lq) ^ (lr & 7);
                a[i] = *(const short8*)&As[row * 64 + cs * 8];
            }
#pragma unroll
            for (int u = 0; u < NW; u++) {
#pragma unroll
                for (int j = 0; j < 4; j++) {
                    int row = wn * 64 + j * 16 + lr;
                    int cs = (kk * 4 + lq) ^ (lr & 7);
                    short8 b = *(const short8*)&Bs[u][row * 64 + cs * 8];
#pragma unroll
                    for (int i = 0; i < 4; i++)
                        acc[u][i][j] = __builtin_amdgcn_mfma_f32_16x16x32_bf16(
                            a[i], b, acc[u][i][j], 0, 0, 0);
                }
            }
        }
    }
    // epilogue: C/D layout col = lane&15, row = (lane>>4)*4 + reg
#pragma unroll
    for (int i = 0; i < 4; i++) {
#pragma unroll
        for (int j = 0; j < 4; j++) {
            int gm = m0 + wm * 64 + i * 16 + lq * 4;
            int gn = n0 + wn * 64 + j * 16 + lr;
#pragma unroll
            for (int r = 0; r < 4; r++) {
                size_t off = (size_t)(gm + r) * ldC + gn;
                if constexpr (DUAL) {
                    float g = acc[0][i][j][r], uu = acc[1][i][j][r];
                    float v = g / (1.0f + expf(-g)) * uu;
                    u16 h = bf16rne(v);
                    OH[off] = h;
                    OL[off] = bf16rne(v - bf16tof(h));
                } else {
                    float v = acc[0][i][j][r];
                    if constexpr (RES) v += Rsrc[off];
                    C[off] = v;
                }
            }
        }
    }
}

// ---------------- legacy in-kernel-convert MFMA GEMM (lm_head, 1-pass) ------
template <int PASSES, int RES, int DUAL>
__global__ __launch_bounds__(256, 2) void k_mfma(const float* __restrict__ A,
                                                 const float* __restrict__ W1,
                                                 const float* __restrict__ W2,
                                                 const float* __restrict__ Rsrc,
                                                 float* __restrict__ C,
                                                 int M, int N, int K) {
    constexpr int PL = (PASSES > 1) ? 2 : 1;
    constexpr int NW = DUAL ? 2 : 1;
    __shared__ u16 As[PL][128 * 32];
    __shared__ u16 Bs[NW][PL][128 * 32];
    int tid = threadIdx.x;
    int m0 = blockIdx.y * 128, n0 = blockIdx.x * 128;
    int w = tid >> 6, lane = tid & 63;
    int wm = w >> 1, wn = w & 1;
    int lr = lane & 15, lq = lane >> 4;
    int aChunk = lq ^ (lr & 3);
    int bChunk = lq ^ ((lr >> 2) & 3);

    f32x4 acc[NW][4][4];
#pragma unroll
    for (int u = 0; u < NW; u++)
#pragma unroll
        for (int i = 0; i < 4; i++)
#pragma unroll
            for (int j = 0; j < 4; j++)
#pragma unroll
                for (int r = 0; r < 4; r++) acc[u][i][j][r] = 0.f;

    const int tA_m = tid >> 3;
    const int tA_k = (tid & 7) * 4;
    const int tB_n = (tid & 31) * 4;
    const int tB_k = (tid >> 5) * 4;

    for (int k0 = 0; k0 < K; k0 += 32) {
        __syncthreads();
#pragma unroll
        for (int p = 0; p < 4; p++) {
            int m = p * 32 + tA_m;
            f4 v = *(const f4*)(A + (size_t)(m0 + m) * K + k0 + tA_k);
            int ch = (tA_k >> 3) ^ (m & 3);
            int idx = m * 32 + ch * 8 + (tA_k & 7);
            ushort4 hv;
            hv.x = bf16rne(v.x); hv.y = bf16rne(v.y);
            hv.z = bf16rne(v.z); hv.w = bf16rne(v.w);
            *(ushort4*)&As[0][idx] = hv;
            if constexpr (PASSES > 1) {
                ushort4 lv;
                lv.x = bf16rne(v.x - bf16tof(hv.x));
                lv.y = bf16rne(v.y - bf16tof(hv.y));
                lv.z = bf16rne(v.z - bf16tof(hv.z));
                lv.w = bf16rne(v.w - bf16tof(hv.w));
                *(ushort4*)&As[1][idx] = lv;
            }
        }
#pragma unroll
        for (int u = 0; u < NW; u++) {
            const float* Wp = (u == 0) ? W1 : W2;
            float bb[4][4];
#pragma unroll
            for (int i = 0; i < 4; i++) {
                f4 v = *(const f4*)(Wp + (size_t)(k0 + tB_k + i) * N + n0 + tB_n);
                bb[i][0] = v.x; bb[i][1] = v.y; bb[i][2] = v.z; bb[i][3] = v.w;
            }
#pragma unroll
            for (int j = 0; j < 4; j++) {
                int row = tB_n + j;
                int ch = (tB_k >> 3) ^ ((row >> 2) & 3);
                int idx = row * 32 + ch * 8 + (tB_k & 7);
                ushort4 hv;
                hv.x = bf16rne(bb[0][j]); hv.y = bf16rne(bb[1][j]);
                hv.z = bf16rne(bb[2][j]); hv.w = bf16rne(bb[3][j]);
                *(ushort4*)&Bs[u][0][idx] = hv;
                if constexpr (PASSES > 1) {
                    ushort4 lv;
                    lv.x = bf16rne(bb[0][j] - bf16tof(hv.x));
                    lv.y = bf16rne(bb[1][j] - bf16tof(hv.y));
                    lv.z = bf16rne(bb[2][j] - bf16tof(hv.z));
                    lv.w = bf16rne(bb[3][j] - bf16tof(hv.w));
                    *(ushort4*)&Bs[u][1][idx] = lv;
                }
            }
        }
        __syncthreads();
        short8 ah[4], al[4];
#pragma unroll
        for (int i = 0; i < 4; i++) {
            int row = wm * 64 + i * 16 + lr;
            ah[i] = *(const short8*)&As[0][row * 32 + aChunk * 8];
            if constexpr (PASSES > 1)
                al[i] = *(const short8*)&As[1][row * 32 + aChunk * 8];
        }
#pragma unroll
        for (int u = 0; u < NW; u++) {
#pragma unroll
            for (int j = 0; j < 4; j++) {
                int row = wn * 64 + j * 16 + lr;
                short8 bh = *(const short8*)&Bs[u][0][row * 32 + bChunk * 8];
#pragma unroll
                for (int i = 0; i < 4; i++)
                    acc[u][i][j] = __builtin_amdgcn_mfma_f32_16x16x32_bf16(
                        ah[i], bh, acc[u][i][j], 0, 0, 0);
                if constexpr (PASSES > 1) {
                    short8 bl = *(const short8*)&Bs[u][1][row * 32 + bChunk * 8];
#pragma unroll
                    for (int i = 0; i < 4; i++) {
                        acc[u][i][j] = __builtin_amdgcn_mfma_f32_16x16x32_bf16(
                            ah[i], bl, acc[u][i][j], 0, 0, 0);
                        acc[u][i][j] = __builtin_amdgcn_mfma_f32_16x16x32_bf16(
                            al[i], bh, acc[u][i][j], 0, 0, 0);
                    }
                }
            }
        }
    }
#pragma unroll
    for (int i = 0; i < 4; i++) {
#pragma unroll
        for (int j = 0; j < 4; j++) {
            int gm = m0 + wm * 64 + i * 16 + lq * 4;
            int gn = n0 + wn * 64 + j * 16 + lr;
#pragma unroll
            for (int r = 0; r < 4; r++) {
                size_t off = (size_t)(gm + r) * N + gn;
                float vv;
                if constexpr (DUAL) {
                    float g = acc[0][i][j][r], uu = acc[1][i][j][r];
                    vv = g / (1.0f + expf(-g)) * uu;
                } else {
                    vv = acc[0][i][j][r];
                }
                if constexpr (RES) vv += Rsrc[off];
                C[off] = vv;
            }
        }
    }
}

// ---------------- RoPE ----------------
__global__ void k_rope_table(float* __restrict__ cosT, float* __restrict__ sinT) {
    int idx = blockIdx.x * blockDim.x + threadIdx.x;
    if (idx >= SSEQ * 64) return;
    int pos = idx >> 6, d = idx & 63;
    float p   = (float)pow(10000.0, (double)d * (1.0 / 64.0));
    float inv = 1.0f / p;
    float ang = (float)pos * inv;
    cosT[idx] = (float)cos((double)ang);
    sinT[idx] = (float)sin((double)ang);
}

__global__ void k_rope(float* __restrict__ Cq, float* __restrict__ Ck,
                       const float* __restrict__ cosT, const float* __restrict__ sinT,
                       int s) {
    int bi = blockIdx.x;
    int h = bi % HH;
    int i = (bi / HH) % s;
    size_t base = (size_t)(bi / HH) * DD + h * DHH;
    int d = threadIdx.x;
    float c  = cosT[i * 64 + d];
    float sn = sinT[i * 64 + d];
    float x1 = Cq[base + d], x2 = Cq[base + 64 + d];
    Cq[base + d]      = x1 * c - x2 * sn;
    Cq[base + 64 + d] = x1 * sn + x2 * c;
    x1 = Ck[base + d]; x2 = Ck[base + 64 + d];
    Ck[base + d]      = x1 * c - x2 * sn;
    Ck[base + 64 + d] = x1 * sn + x2 * c;
}

// ---------------- flash attention fp32 -> bf16x2 output planes ----------------
__global__ __launch_bounds__(256, 2) void k_attn(const float* __restrict__ Q,
                                                 const float* __restrict__ K,
                                                 const float* __restrict__ V,
                                                 const int* __restrict__ mask,
                                                 u16* __restrict__ OH,
                                                 u16* __restrict__ OL, int s) {
    int qt = blockIdx.x, bh = blockIdx.y;
    int h = bh & (HH - 1), b = bh >> 4;
    __shared__ float Qs[64][132];
    __shared__ float Ks[32 * 128];
    __shared__ float Vs[32][132];
    __shared__ float Ps[64][36];
    __shared__ float mrow[64], lrow[64];
    int tid = threadIdx.x;
    int tx = tid & 15, ty = tid >> 4;

#pragma unroll
    for (int p = 0; p < 2; p++) {
        int r = p * 32 + (tid >> 3);
        int kb = (tid & 7) * 4;
        const float* src = Q + (size_t)(b * s + qt * 64 + r) * DD + h * DHH;
#pragma unroll
        for (int q = 0; q < 4; q++)
            *(f4*)&Qs[r][kb + 32 * q] = *(const f4*)(src + kb + 32 * q);
    }
    if (tid < 64) { mrow[tid] = -3.0e38f; lrow[tid] = 0.f; }

    float acc[4][8];
#pragma unroll
    for (int i = 0; i < 4; i++)
#pragma unroll
        for (int c = 0; c < 8; c++) acc[i][c] = 0.f;
    const float scale = 0.08838834764831845f;

    int ktmax = 2 * (qt + 1);
    for (int kt = 0; kt < ktmax; kt++) {
        __syncthreads();
#pragma unroll
        for (int p = 0; p < 4; p++) {
            int c = p * 8 + (tid >> 5);
            int kk = (tid & 31) * 4;
            size_t g = (size_t)(b * s + kt * 32 + c) * DD + h * DHH + kk;
            f4 kv = *(const f4*)(K + g);
            int ch = (kk >> 2) ^ (c >> 1);
            *(f4*)&Ks[c * 128 + ch * 4] = kv;
            *(f4*)&Vs[c][kk] = *(const f4*)(V + g);
        }
        __syncthreads();
        float sv[4][2];
#pragma unroll
        for (int i = 0; i < 4; i++) { sv[i][0] = 0.f; sv[i][1] = 0.f; }
        for (int kk = 0; kk < 128; kk += 4) {
            f4 qv[4];
#pragma unroll
            for (int i = 0; i < 4; i++) qv[i] = *(const f4*)&Qs[ty * 4 + i][kk];
#pragma unroll
            for (int j = 0; j < 2; j++) {
                int c = tx * 2 + j;
                int ch = (kk >> 2) ^ (c >> 1);
                f4 kv = *(const f4*)&Ks[c * 128 + ch * 4];
#pragma unroll
                for (int i = 0; i < 4; i++)
                    sv[i][j] += qv[i].x * kv.x + qv[i].y * kv.y +
                                qv[i].z * kv.z + qv[i].w * kv.w;
            }
        }
        float scl[4];
#pragma unroll
        for (int i = 0; i < 4; i++) {
            int r = ty * 4 + i;
            int igl = qt * 64 + r;
#pragma unroll
            for (int j = 0; j < 2; j++) {
                int jg = kt * 32 + tx * 2 + j;
                bool ok = (jg <= igl) && (mask[b * s + jg] > 0);
                sv[i][j] = ok ? sv[i][j] * scale : -1.0e9f;
            }
            float rmax = fmaxf(sv[i][0], sv[i][1]);
            rmax = fmaxf(rmax, __shfl_xor(rmax, 1));
            rmax = fmaxf(rmax, __shfl_xor(rmax, 2));
            rmax = fmaxf(rmax, __shfl_xor(rmax, 4));
            rmax = fmaxf(rmax, __shfl_xor(rmax, 8));
            float mold = mrow[r];
            float mnew = fmaxf(mold, rmax);
            float p0 = expf(sv[i][0] - mnew);
            float p1 = expf(sv[i][1] - mnew);
            float ps = p0 + p1;
            ps += __shfl_xor(ps, 1);
            ps += __shfl_xor(ps, 2);
            ps += __shfl_xor(ps, 4);
            ps += __shfl_xor(ps, 8);
            scl[i] = expf(mold - mnew);
            if (tx == 0) { mrow[r] = mnew; lrow[r] = lrow[r] * scl[i] + ps; }
            float2 pw; pw.x = p0; pw.y = p1;
            *(float2*)&Ps[r][tx * 2] = pw;
        }
        __syncthreads();
#pragma unroll
        for (int i = 0; i < 4; i++) {
            float sc = scl[i];
#pragma unroll
            for (int c = 0; c < 8; c++) acc[i][c] *= sc;
        }
        for (int jj = 0; jj < 32; jj += 4) {
            f4 pv[4];
#pragma unroll
            for (int i = 0; i < 4; i++) pv[i] = *(const f4*)&Ps[ty * 4 + i][jj];
#pragma unroll
            for (int j2 = 0; j2 < 4; j2++) {
                f4 va = *(const f4*)&Vs[jj + j2][tx * 4];
                f4 vb = *(const f4*)&Vs[jj + j2][64 + tx * 4];
#pragma unroll
                for (int i = 0; i < 4; i++) {
                    float p = (&pv[i].x)[j2];
                    acc[i][0] += p * va.x; acc[i][1] += p * va.y;
                    acc[i][2] += p * va.z; acc[i][3] += p * va.w;
                    acc[i][4] += p * vb.x; acc[i][5] += p * vb.y;
                    acc[i][6] += p * vb.z; acc[i][7] += p * vb.w;
                }
            }
        }
    }
    __syncthreads();
#pragma unroll
    for (int i = 0; i < 4; i++) {
        int r = ty * 4 + i;
        float linv = 1.0f / lrow[r];
        size_t ob = (size_t)(b * s + qt * 64 + r) * DD + h * DHH;
        ushort4 h1, l1, h2, l2;
        u16 *h1p = (u16*)&h1, *l1p = (u16*)&l1, *h2p = (u16*)&h2, *l2p = (u16*)&l2;
#pragma unroll
        for (int c = 0; c < 4; c++) {
            float v = acc[i][c] * linv;
            u16 hh = bf16rne(v);
            h1p[c] = hh; l1p[c] = bf16rne(v - bf16tof(hh));
            float v2 = acc[i][c + 4] * linv;
            u16 hh2 = bf16rne(v2);
            h2p[c] = hh2; l2p[c] = bf16rne(v2 - bf16tof(hh2));
        }
        *(ushort4*)&OH[ob + tx * 4] = h1;
        *(ushort4*)&OL[ob + tx * 4] = l1;
        *(ushort4*)&OH[ob + 64 + tx * 4] = h2;
        *(ushort4*)&OL[ob + 64 + tx * 4] = l2;
    }
}

// ---------------- prune scoring / selection ----------------
__global__ __launch_bounds__(256) void k_score(const float* __restrict__ Hb,
                                               const float* __restrict__ srow,
                                               float* __restrict__ sc) {
    int row = blockIdx.x;
    const float* xr = Hb + (size_t)row * DD;
    float ss = 0.f;
    for (int i = threadIdx.x; i < DD / 4; i += blockDim.x) {
        f4 a = ((const f4*)xr)[i];
        f4 w = ((const f4*)srow)[i];
        ss += a.x * w.x + a.y * w.y + a.z * w.z + a.w * w.w;
    }
    for (int o = 32; o > 0; o >>= 1) ss += __shfl_down(ss, o);
    __shared__ float red[4];
    int wid = threadIdx.x >> 6, lane = threadIdx.x & 63;
    if (lane == 0) red[wid] = ss;
    __syncthreads();
    if (threadIdx.x == 0) sc[row] = red[0] + red[1] + red[2] + red[3];
}

__global__ __launch_bounds__(256) void k_rank(const float* __restrict__ sc,
                                              int* __restrict__ flg, int s, int kk) {
    int b = blockIdx.x / s, i = blockIdx.x % s;
    const float* scb = sc + (size_t)b * s;
    float vi = scb[i];
    int cnt = 0;
    for (int j = threadIdx.x; j < s; j += 256) {
        float vj = scb[j];
        if (vj > vi || (vj == vi && j < i)) cnt++;
    }
    for (int o = 32; o > 0; o >>= 1) cnt += __shfl_down(cnt, o);
    __shared__ int red[4];
    int wid = threadIdx.x >> 6, lane = threadIdx.x & 63;
    if (lane == 0) red[wid] = cnt;
    __syncthreads();
    if (threadIdx.x == 0) flg[b * s + i] = ((red[0] + red[1] + red[2] + red[3]) < kk) ? 1 : 0;
}

__global__ void k_compact(const int* __restrict__ flg, int* __restrict__ idx, int s, int kk) {
    int b = blockIdx.x;
    if (threadIdx.x == 0) {
        int p = 0;
        for (int i = 0; i < s; i++)
            if (flg[b * s + i]) idx[b * kk + (p++)] = i;
    }
}

__global__ void k_gather(const float* __restrict__ Hin, const int* __restrict__ idx,
                         float* __restrict__ Hout, int s, int kk) {
    int row = blockIdx.x;
    int b = row / kk, p = row % kk;
    int i = idx[b * kk + p];
    const f4* src = (const f4*)(Hin + (size_t)(b * s + i) * DD);
    f4* dst = (f4*)(Hout + (size_t)row * DD);
    for (int t = threadIdx.x; t < DD / 4; t += blockDim.x) dst[t] = src[t];
}

__global__ void k_gather_mask(const int* __restrict__ Min, const int* __restrict__ idx,
                              int* __restrict__ Mout, int s, int kk) {
    int t = blockIdx.x * blockDim.x + threadIdx.x;
    if (t < BBATCH * kk) {
        int b = t / kk, p = t % kk;
        Mout[t] = Min[b * s + idx[b * kk + p]];
    }
}

// ---------------------------------------------------------------------------
extern "C" void kernel_launch(void* const* d_in, const int* in_sizes, int n_in,
                              void* d_out, int out_size, void* d_ws, size_t ws_size,
                              hipStream_t stream) {
    const int*   input_ids = (const int*)d_in[0];
    const int*   attn_mask = (const int*)d_in[1];
    const float* embed     = (const float*)d_in[2];
    const float* wq        = (const float*)d_in[3];
    const float* wk        = (const float*)d_in[4];
    const float* wv        = (const float*)d_in[5];
    const float* wo        = (const float*)d_in[6];
    const float* wg        = (const float*)d_in[7];
    const float* wu        = (const float*)d_in[8];
    const float* wd        = (const float*)d_in[9];
    const float* ln1       = (const float*)d_in[10];
    const float* ln2       = (const float*)d_in[11];
    const float* lnf       = (const float*)d_in[12];
    const float* lm_head   = (const float*)d_in[13];
    const float* scorer    = (const float*)d_in[14];

    float* ws = (float*)d_ws;
    const size_t R_HD = (size_t)BBATCH * SSEQ * DD;   // 8,388,608 floats
    float* H0  = ws;
    float* H1  = ws + R_HD;
    float* CQ  = ws + 2 * R_HD;
    float* CK  = ws + 3 * R_HD;
    float* CV  = ws + 4 * R_HD;
    u16*   AHD = (u16*)(ws + 5 * R_HD);               // [4096][2048] bf16 hi
    u16*   ALD = AHD + (size_t)4096 * DD;             // lo plane
    float* COS = ws + 6 * R_HD;
    float* SIN = COS + SSEQ * 64;
    float* SC  = SIN + SSEQ * 64;
    int*   FLG = (int*)(SC + (size_t)BBATCH * SSEQ);
    int*   IDX = FLG + BBATCH * SSEQ;
    int*   M0  = IDX + BBATCH * SSEQ;
    int*   M1  = M0 + BBATCH * SSEQ;

    k_rope_table<<<(SSEQ * 64 + 255) / 256, 256, 0, stream>>>(COS, SIN);
    k_embed<<<BBATCH * SSEQ, 256, 0, stream>>>(input_ids, embed, H0);
    k_copy_int<<<(BBATCH * SSEQ + 255) / 256, 256, 0, stream>>>(attn_mask, M0, BBATCH * SSEQ);

    float* Hc = H0; float* Nc = H1;
    int*   Mc = M0; int*   Mt = M1;
    int s = SSEQ;

    for (int l = 0; l < LLAYERS; l++) {
        if (l == 1 || l == 2) {
            int pi = l - 1;
            int kk = s / 2;
            k_score<<<BBATCH * s, 256, 0, stream>>>(Hc, scorer + (size_t)pi * 2 * DD, SC);
            k_rank<<<BBATCH * s, 256, 0, stream>>>(SC, FLG, s, kk);
            k_compact<<<BBATCH, 64, 0, stream>>>(FLG, IDX, s, kk);
            k_gather<<<BBATCH * kk, 256, 0, stream>>>(Hc, IDX, Nc, s, kk);
            k_gather_mask<<<(BBATCH * kk + 255) / 256, 256, 0, stream>>>(Mc, IDX, Mt, s, kk);
            { float* t = Hc; Hc = Nc; Nc = t; }
            { int* t = Mc; Mc = Mt; Mt = t; }
            s = kk;
        }
        int rows = BBATCH * s;
        const float* Wq = wq + (size_t)l * DD * DD;
        const float* Wk = wk + (size_t)l * DD * DD;
        const float* Wv = wv + (size_t)l * DD * DD;
        const float* Wo = wo + (size_t)l * DD * DD;
        const float* Wg = wg + (size_t)l * DD * FFF;
        const float* Wu = wu + (size_t)l * DD * FFF;
        const float* Wd = wd + (size_t)l * FFF * DD;
        const float* L1 = ln1 + (size_t)l * DD;
        const float* L2 = ln2 + (size_t)l * DD;

        u16* Wt = (u16*)Nc;   // 16.8 MB region inside idle Nc buffer

        // ---- attention path ----
        k_rmsnorm_cvt<<<rows, 256, 0, stream>>>(Hc, L1, AHD, ALD);
        dim3 gW(DD / 64, DD / 64);
        dim3 gG(DD / 128, rows / 128);
        k_cvt_w<<<gW, 256, 0, stream>>>(Wq, Wt, DD, DD, 0);
        k_bgemm<0, 0><<<gG, 256, 0, stream>>>(AHD, ALD, Wt, nullptr, nullptr, CQ,
                                              nullptr, nullptr, rows, DD, DD);
        k_cvt_w<<<gW, 256, 0, stream>>>(Wk, Wt, DD, DD, 0);
        k_bgemm<0, 0><<<gG, 256, 0, stream>>>(AHD, ALD, Wt, nullptr, nullptr, CK,
                                              nullptr, nullptr, rows, DD, DD);
        k_cvt_w<<<gW, 256, 0, stream>>>(Wv, Wt, DD, DD, 0);
        k_bgemm<0, 0><<<gG, 256, 0, stream>>>(AHD, ALD, Wt, nullptr, nullptr, CV,
                                              nullptr, nullptr, rows, DD, DD);
        k_rope<<<rows * HH, 64, 0, stream>>>(CQ, CK, COS, SIN, s);
        k_attn<<<dim3(s / 64, BBATCH * HH), 256, 0, stream>>>(CQ, CK, CV, Mc, AHD, ALD, s);
        k_cvt_w<<<gW, 256, 0, stream>>>(Wo, Wt, DD, DD, 0);
        k_bgemm<1, 0><<<gG, 256, 0, stream>>>(AHD, ALD, Wt, nullptr, Hc, Hc,
                                              nullptr, nullptr, rows, DD, DD);

        // ---- MLP ----
        k_rmsnorm_cvt<<<rows, 256, 0, stream>>>(Hc, L2, AHD, ALD);
        u16* AHF = (u16*)CQ;   // [MC][8192] hi
        u16* ALF = (u16*)CK;   // lo
        u16* WgT = (u16*)CV;   // [2048][4096]
        u16* WuT = WgT + (size_t)2048 * 2 * DD;
        int MC  = (rows < 2048) ? rows : 2048;
        int nMC = rows / MC;
        for (int mc = 0; mc < nMC; mc++) {
            const u16* AHin = AHD + (size_t)mc * MC * DD;
            const u16* ALin = ALD + (size_t)mc * MC * DD;
            for (int nf = 0; nf < FFF; nf += 2048) {
                k_cvt_w<<<dim3(2048 / 64, DD / 64), 256, 0, stream>>>(Wg, WgT, DD, FFF, nf);
                k_cvt_w<<<dim3(2048 / 64, DD / 64), 256, 0, stream>>>(Wu, WuT, DD, FFF, nf);
                k_bgemm<0, 1><<<dim3(2048 / 128, MC / 128), 256, 0, stream>>>(
                    AHin, ALin, WgT, WuT, nullptr, nullptr,
                    AHF + nf, ALF + nf, MC, FFF, DD);
            }
            for (int nd = 0; nd < DD; nd += 1024) {
                k_cvt_w<<<dim3(1024 / 64, FFF / 64), 256, 0, stream>>>(Wd, (u16*)CV, FFF, DD, nd);
                float* Cb = Hc + (size_t)mc * MC * DD + nd;
                k_bgemm<1, 0><<<dim3(1024 / 128, MC / 128), 256, 0, stream>>>(
                    AHF, ALF, (u16*)CV, nullptr, Cb, Cb,
                    nullptr, nullptr, MC, DD, FFF);
            }
        }
    }

    // final rmsnorm + lm_head (legacy 1-pass bf16 kernel, fp32 A in CQ region)
    int rows = BBATCH * s;   // 1024
    k_rmsnorm<<<rows, 256, 0, stream>>>(Hc, lnf, CQ);
    k_mfma<1, 0, 0><<<dim3(VV / 128, rows / 128), 256, 0, stream>>>(
        CQ, lm_head, nullptr, nullptr, (float*)d_out, rows, VV, DD);
}

// Round 4
// 7757.549 us; speedup vs baseline: 2.5939x; 2.5939x over previous
//
#include <hip/hip_runtime.h>
#include <math.h>

// ---------------------------------------------------------------------------
// SDTP forward, round 4.
// - All weights converted to separate bf16 HI/LO planes exactly ONCE per fwd.
// - k_bgemm: clean bf16 MFMA GEMM, phases (Ah*Wh, Ah*Wl, Al*Wh) via pointer
//   swap per phase. PASSES=3 for layers 0,1 (feed prune scorers), PASSES=1
//   for layers 2,3 + lm_head (post-prune, output tolerance only).
// - Tier A (ws >= ~471MB): full-size planes, full grids, no chunking.
//   Tier D (ws >= ~203MB): MLP chunked over FF with split-K accumulation,
//   conversions hoisted, same kernels.
// - Attention: exact fp32 register-tiled flash (unchanged, writes planes).
// ---------------------------------------------------------------------------

#define DD 2048
#define HH 16
#define DHH 128
#define FFF 8192
#define BBATCH 2
#define SSEQ 2048
#define VV 32000
#define LLAYERS 4

typedef float4 f4;
typedef __attribute__((ext_vector_type(8))) short short8;
typedef __attribute__((ext_vector_type(4))) float f32x4;
typedef unsigned short u16;

__device__ inline u16 bf16rne(float x) {
    unsigned u = __float_as_uint(x);
    unsigned r = (u + 0x7FFFu + ((u >> 16) & 1u)) >> 16;
    return (u16)r;
}
__device__ inline float bf16tof(u16 h) {
    return __uint_as_float(((unsigned)h) << 16);
}

// ---------------- embedding / copies ----------------
__global__ void k_embed(const int* __restrict__ ids, const float* __restrict__ emb,
                        float* __restrict__ out) {
    int row = blockIdx.x;
    int id  = ids[row];
    const f4* src = (const f4*)(emb + (size_t)id * DD);
    f4*       dst = (f4*)(out + (size_t)row * DD);
    for (int i = threadIdx.x; i < DD / 4; i += blockDim.x) dst[i] = src[i];
}

__global__ void k_copy_int(const int* __restrict__ src, int* __restrict__ dst, int n) {
    int i = blockIdx.x * blockDim.x + threadIdx.x;
    if (i < n) dst[i] = src[i];
}

// ---------------- rmsnorm fp32 ----------------
__global__ __launch_bounds__(256) void k_rmsnorm(const float* __restrict__ x,
                                                 const float* __restrict__ w,
                                                 float* __restrict__ out) {
    int row = blockIdx.x;
    const float* xr = x + (size_t)row * DD;
    float ss = 0.f;
    for (int i = threadIdx.x; i < DD / 4; i += blockDim.x) {
        f4 v = ((const f4*)xr)[i];
        ss += v.x * v.x + v.y * v.y + v.z * v.z + v.w * v.w;
    }
    for (int o = 32; o > 0; o >>= 1) ss += __shfl_down(ss, o);
    __shared__ float red[4];
    int wid = threadIdx.x >> 6, lane = threadIdx.x & 63;
    if (lane == 0) red[wid] = ss;
    __syncthreads();
    float tot = red[0] + red[1] + red[2] + red[3];
    float inv = 1.0f / sqrtf(tot / (float)DD + 1e-6f);
    float* orow = out + (size_t)row * DD;
    for (int i = threadIdx.x; i < DD / 4; i += blockDim.x) {
        f4 v = ((const f4*)xr)[i];
        f4 wv = ((const f4*)w)[i];
        f4 o;
        o.x = v.x * wv.x * inv; o.y = v.y * wv.y * inv;
        o.z = v.z * wv.z * inv; o.w = v.w * wv.w * inv;
        ((f4*)orow)[i] = o;
    }
}

// ---------------- rmsnorm -> bf16 hi/lo planes ----------------
__global__ __launch_bounds__(256) void k_rmsnorm_cvt(const float* __restrict__ x,
                                                     const float* __restrict__ w,
                                                     u16* __restrict__ OH,
                                                     u16* __restrict__ OL) {
    int row = blockIdx.x;
    const float* xr = x + (size_t)row * DD;
    float ss = 0.f;
    for (int i = threadIdx.x; i < DD / 4; i += blockDim.x) {
        f4 v = ((const f4*)xr)[i];
        ss += v.x * v.x + v.y * v.y + v.z * v.z + v.w * v.w;
    }
    for (int o = 32; o > 0; o >>= 1) ss += __shfl_down(ss, o);
    __shared__ float red[4];
    int wid = threadIdx.x >> 6, lane = threadIdx.x & 63;
    if (lane == 0) red[wid] = ss;
    __syncthreads();
    float tot = red[0] + red[1] + red[2] + red[3];
    float inv = 1.0f / sqrtf(tot / (float)DD + 1e-6f);
    for (int i = threadIdx.x; i < DD / 4; i += blockDim.x) {
        f4 v = ((const f4*)xr)[i];
        f4 wv = ((const f4*)w)[i];
        float o[4];
        o[0] = v.x * wv.x * inv; o[1] = v.y * wv.y * inv;
        o[2] = v.z * wv.z * inv; o[3] = v.w * wv.w * inv;
        ushort4 hv, lv;
        u16* hp = (u16*)&hv; u16* lp = (u16*)&lv;
#pragma unroll
        for (int j = 0; j < 4; j++) {
            u16 h = bf16rne(o[j]);
            hp[j] = h;
            lp[j] = bf16rne(o[j] - bf16tof(h));
        }
        *(ushort4*)&OH[(size_t)row * DD + i * 4] = hv;
        *(ushort4*)&OL[(size_t)row * DD + i * 4] = lv;
    }
}

// ---------------- weight transpose+convert: W[K][N] -> planes [n][K] -------
// grid (nch/64, K/64); WtH/WtL row-major, leading dim K; n LOCAL to chunk.
__global__ __launch_bounds__(256) void k_cvt_w(const float* __restrict__ W,
                                               u16* __restrict__ WtH,
                                               u16* __restrict__ WtL,
                                               int K, int N, int nc0) {
    __shared__ float T[64][65];
    int tid = threadIdx.x;
    int n0g = nc0 + blockIdx.x * 64;
    int k0  = blockIdx.y * 64;
#pragma unroll
    for (int it = 0; it < 4; it++) {
        int r = it * 16 + (tid >> 4);
        int c4 = (tid & 15) * 4;
        f4 v = *(const f4*)(W + (size_t)(k0 + r) * N + n0g + c4);
        T[r][c4 + 0] = v.x; T[r][c4 + 1] = v.y;
        T[r][c4 + 2] = v.z; T[r][c4 + 3] = v.w;
    }
    __syncthreads();
    int nl = tid >> 2;
    int ks = (tid & 3) * 16;
    u16 hi[16], lo[16];
#pragma unroll
    for (int j = 0; j < 16; j++) {
        float v = T[ks + j][nl];
        u16 h = bf16rne(v);
        hi[j] = h;
        lo[j] = bf16rne(v - bf16tof(h));
    }
    size_t base = (size_t)(blockIdx.x * 64 + nl) * K + k0 + ks;
    *(short8*)&WtH[base]     = *(short8*)&hi[0];
    *(short8*)&WtH[base + 8] = *(short8*)&hi[8];
    *(short8*)&WtL[base]     = *(short8*)&lo[0];
    *(short8*)&WtL[base + 8] = *(short8*)&lo[8];
}

// ---------------- bf16 MFMA GEMM over PASSES phases ----------------
// A planes [M][K]; B planes [n][K] (n local). Phase 0: Ah*Bh, 1: Ah*Bl,
// 2: Al*Bh. Block 128x128, BK=64, 4 waves (2x2), 16x16x32 MFMA.
// DUAL: two B's, epilogue silu(g)*u -> planes OH/OL; else fp32 C (+Rsrc).
__device__ inline void stage_tile(const u16* __restrict__ src, int ld,
                                  u16* __restrict__ lds, int tid) {
#pragma unroll
    for (int it = 0; it < 4; it++) {
        int row = it * 32 + (tid >> 3);
        int c   = tid & 7;
        int cs  = c ^ (row & 7);
        short8 v = *(const short8*)(src + (size_t)row * ld + c * 8);
        *(short8*)&lds[row * 64 + cs * 8] = v;
    }
}

template <int PASSES, int RES, int DUAL>
__global__ __launch_bounds__(256, 2) void k_bgemm(const u16* __restrict__ AH,
                                                  const u16* __restrict__ AL,
                                                  const u16* __restrict__ B1H,
                                                  const u16* __restrict__ B1L,
                                                  const u16* __restrict__ B2H,
                                                  const u16* __restrict__ B2L,
                                                  const float* __restrict__ Rsrc,
                                                  float* __restrict__ C,
                                                  u16* __restrict__ OH,
                                                  u16* __restrict__ OL,
                                                  int M, int ldC, int K) {
    constexpr int NW = DUAL ? 2 : 1;
    __shared__ u16 As[128 * 64];
    __shared__ u16 Bs[NW][128 * 64];
    int tid = threadIdx.x;
    int m0 = blockIdx.y * 128, n0 = blockIdx.x * 128;
    int lane = tid & 63, w = tid >> 6;
    int wm = w >> 1, wn = w & 1;
    int lr = lane & 15, lq = lane >> 4;

    f32x4 acc[NW][4][4];
#pragma unroll
    for (int u = 0; u < NW; u++)
#pragma unroll
        for (int i = 0; i < 4; i++)
#pragma unroll
            for (int j = 0; j < 4; j++)
#pragma unroll
                for (int r = 0; r < 4; r++) acc[u][i][j][r] = 0.f;

    const int KT = PASSES * K;
    for (int kb = 0; kb < KT; kb += 64) {
        int p  = (PASSES > 1) ? ((kb >= 2 * K) ? 2 : ((kb >= K) ? 1 : 0)) : 0;
        int ks = kb - p * K;
        const u16* Ap  = ((p == 2) ? AL  : AH)  + (size_t)m0 * K + ks;
        const u16* B1p = ((p == 1) ? B1L : B1H) + (size_t)n0 * K + ks;
        __syncthreads();
        stage_tile(Ap, K, As, tid);
        stage_tile(B1p, K, Bs[0], tid);
        if constexpr (DUAL) {
            const u16* B2p = ((p == 1) ? B2L : B2H) + (size_t)n0 * K + ks;
            stage_tile(B2p, K, Bs[1], tid);
        }
        __syncthreads();
#pragma unroll
        for (int kk = 0; kk < 2; kk++) {
            short8 a[4];
#pragma unroll
            for (int i = 0; i < 4; i++) {
                int row = wm * 64 + i * 16 + lr;
                int cs = (kk * 4 + lq) ^ (lr & 7);
                a[i] = *(const short8*)&As[row * 64 + cs * 8];
            }
#pragma unroll
            for (int u = 0; u < NW; u++) {
#pragma unroll
                for (int j = 0; j < 4; j++) {
                    int row = wn * 64 + j * 16 + lr;
                    int cs = (kk * 4 + lq) ^ (lr & 7);
                    short8 b = *(const short8*)&Bs[u][row * 64 + cs * 8];
#pragma unroll
                    for (int i = 0; i < 4; i++)
                        acc[u][i][j] = __builtin_amdgcn_mfma_f32_16x16x32_bf16(
                            a[i], b, acc[u][i][j], 0, 0, 0);
                }
            }
        }
    }
#pragma unroll
    for (int i = 0; i < 4; i++) {
#pragma unroll
        for (int j = 0; j < 4; j++) {
            int gm = m0 + wm * 64 + i * 16 + lq * 4;
            int gn = n0 + wn * 64 + j * 16 + lr;
#pragma unroll
            for (int r = 0; r < 4; r++) {
                size_t off = (size_t)(gm + r) * ldC + gn;
                if constexpr (DUAL) {
                    float g = acc[0][i][j][r], uu = acc[1][i][j][r];
                    float v = g / (1.0f + expf(-g)) * uu;
                    u16 h = bf16rne(v);
                    OH[off] = h;
                    OL[off] = bf16rne(v - bf16tof(h));
                } else {
                    float v = acc[0][i][j][r];
                    if constexpr (RES) v += Rsrc[off];
                    C[off] = v;
                }
            }
        }
    }
}

// ---------------- legacy in-kernel-convert MFMA GEMM (lm_head) ----------------
template <int PASSES, int RES>
__global__ __launch_bounds__(256, 2) void k_mfma(const float* __restrict__ A,
                                                 const float* __restrict__ W1,
                                                 const float* __restrict__ Rsrc,
                                                 float* __restrict__ C,
                                                 int M, int N, int K) {
    constexpr int PL = (PASSES > 1) ? 2 : 1;
    __shared__ u16 As[PL][128 * 32];
    __shared__ u16 Bs[PL][128 * 32];
    int tid = threadIdx.x;
    int m0 = blockIdx.y * 128, n0 = blockIdx.x * 128;
    int w = tid >> 6, lane = tid & 63;
    int wm = w >> 1, wn = w & 1;
    int lr = lane & 15, lq = lane >> 4;
    int aChunk = lq ^ (lr & 3);
    int bChunk = lq ^ ((lr >> 2) & 3);

    f32x4 acc[4][4];
#pragma unroll
    for (int i = 0; i < 4; i++)
#pragma unroll
        for (int j = 0; j < 4; j++)
#pragma unroll
            for (int r = 0; r < 4; r++) acc[i][j][r] = 0.f;

    const int tA_m = tid >> 3;
    const int tA_k = (tid & 7) * 4;
    const int tB_n = (tid & 31) * 4;
    const int tB_k = (tid >> 5) * 4;

    for (int k0 = 0; k0 < K; k0 += 32) {
        __syncthreads();
#pragma unroll
        for (int p = 0; p < 4; p++) {
            int m = p * 32 + tA_m;
            f4 v = *(const f4*)(A + (size_t)(m0 + m) * K + k0 + tA_k);
            int ch = (tA_k >> 3) ^ (m & 3);
            int idx = m * 32 + ch * 8 + (tA_k & 7);
            ushort4 hv;
            hv.x = bf16rne(v.x); hv.y = bf16rne(v.y);
            hv.z = bf16rne(v.z); hv.w = bf16rne(v.w);
            *(ushort4*)&As[0][idx] = hv;
            if constexpr (PASSES > 1) {
                ushort4 lv;
                lv.x = bf16rne(v.x - bf16tof(hv.x));
                lv.y = bf16rne(v.y - bf16tof(hv.y));
                lv.z = bf16rne(v.z - bf16tof(hv.z));
                lv.w = bf16rne(v.w - bf16tof(hv.w));
                *(ushort4*)&As[1][idx] = lv;
            }
        }
        {
            float bb[4][4];
#pragma unroll
            for (int i = 0; i < 4; i++) {
                f4 v = *(const f4*)(W1 + (size_t)(k0 + tB_k + i) * N + n0 + tB_n);
                bb[i][0] = v.x; bb[i][1] = v.y; bb[i][2] = v.z; bb[i][3] = v.w;
            }
#pragma unroll
            for (int j = 0; j < 4; j++) {
                int row = tB_n + j;
                int ch = (tB_k >> 3) ^ ((row >> 2) & 3);
                int idx = row * 32 + ch * 8 + (tB_k & 7);
                ushort4 hv;
                hv.x = bf16rne(bb[0][j]); hv.y = bf16rne(bb[1][j]);
                hv.z = bf16rne(bb[2][j]); hv.w = bf16rne(bb[3][j]);
                *(ushort4*)&Bs[0][idx] = hv;
                if constexpr (PASSES > 1) {
                    ushort4 lv;
                    lv.x = bf16rne(bb[0][j] - bf16tof(hv.x));
                    lv.y = bf16rne(bb[1][j] - bf16tof(hv.y));
                    lv.z = bf16rne(bb[2][j] - bf16tof(hv.z));
                    lv.w = bf16rne(bb[3][j] - bf16tof(hv.w));
                    *(ushort4*)&Bs[1][idx] = lv;
                }
            }
        }
        __syncthreads();
        short8 ah[4], al[4];
#pragma unroll
        for (int i = 0; i < 4; i++) {
            int row = wm * 64 + i * 16 + lr;
            ah[i] = *(const short8*)&As[0][row * 32 + aChunk * 8];
            if constexpr (PASSES > 1)
                al[i] = *(const short8*)&As[1][row * 32 + aChunk * 8];
        }
#pragma unroll
        for (int j = 0; j < 4; j++) {
            int row = wn * 64 + j * 16 + lr;
            short8 bh = *(const short8*)&Bs[0][row * 32 + bChunk * 8];
#pragma unroll
            for (int i = 0; i < 4; i++)
                acc[i][j] = __builtin_amdgcn_mfma_f32_16x16x32_bf16(
                    ah[i], bh, acc[i][j], 0, 0, 0);
            if constexpr (PASSES > 1) {
                short8 bl = *(const short8*)&Bs[1][row * 32 + bChunk * 8];
#pragma unroll
                for (int i = 0; i < 4; i++) {
                    acc[i][j] = __builtin_amdgcn_mfma_f32_16x16x32_bf16(
                        ah[i], bl, acc[i][j], 0, 0, 0);
                    acc[i][j] = __builtin_amdgcn_mfma_f32_16x16x32_bf16(
                        al[i], bh, acc[i][j], 0, 0, 0);
                }
            }
        }
    }
#pragma unroll
    for (int i = 0; i < 4; i++) {
#pragma unroll
        for (int j = 0; j < 4; j++) {
            int gm = m0 + wm * 64 + i * 16 + lq * 4;
            int gn = n0 + wn * 64 + j * 16 + lr;
#pragma unroll
            for (int r = 0; r < 4; r++) {
                size_t off = (size_t)(gm + r) * N + gn;
                float vv = acc[i][j][r];
                if constexpr (RES) vv += Rsrc[off];
                C[off] = vv;
            }
        }
    }
}

// ---------------- RoPE ----------------
__global__ void k_rope_table(float* __restrict__ cosT, float* __restrict__ sinT) {
    int idx = blockIdx.x * blockDim.x + threadIdx.x;
    if (idx >= SSEQ * 64) return;
    int pos = idx >> 6, d = idx & 63;
    float p   = (float)pow(10000.0, (double)d * (1.0 / 64.0));
    float inv = 1.0f / p;
    float ang = (float)pos * inv;
    cosT[idx] = (float)cos((double)ang);
    sinT[idx] = (float)sin((double)ang);
}

__global__ void k_rope(float* __restrict__ Cq, float* __restrict__ Ck,
                       const float* __restrict__ cosT, const float* __restrict__ sinT,
                       int s) {
    int bi = blockIdx.x;
    int h = bi % HH;
    int i = (bi / HH) % s;
    size_t base = (size_t)(bi / HH) * DD + h * DHH;
    int d = threadIdx.x;
    float c  = cosT[i * 64 + d];
    float sn = sinT[i * 64 + d];
    float x1 = Cq[base + d], x2 = Cq[base + 64 + d];
    Cq[base + d]      = x1 * c - x2 * sn;
    Cq[base + 64 + d] = x1 * sn + x2 * c;
    x1 = Ck[base + d]; x2 = Ck[base + 64 + d];
    Ck[base + d]      = x1 * c - x2 * sn;
    Ck[base + 64 + d] = x1 * sn + x2 * c;
}

// ---------------- flash attention fp32 -> bf16x2 output planes ---------------
__global__ __launch_bounds__(256, 2) void k_attn(const float* __restrict__ Q,
                                                 const float* __restrict__ K,
                                                 const float* __restrict__ V,
                                                 const int* __restrict__ mask,
                                                 u16* __restrict__ OH,
                                                 u16* __restrict__ OL, int s) {
    int qt = blockIdx.x, bh = blockIdx.y;
    int h = bh & (HH - 1), b = bh >> 4;
    __shared__ float Qs[64][132];
    __shared__ float Ks[32 * 128];
    __shared__ float Vs[32][132];
    __shared__ float Ps[64][36];
    __shared__ float mrow[64], lrow[64];
    int tid = threadIdx.x;
    int tx = tid & 15, ty = tid >> 4;

#pragma unroll
    for (int p = 0; p < 2; p++) {
        int r = p * 32 + (tid >> 3);
        int kb = (tid & 7) * 4;
        const float* src = Q + (size_t)(b * s + qt * 64 + r) * DD + h * DHH;
#pragma unroll
        for (int q = 0; q < 4; q++)
            *(f4*)&Qs[r][kb + 32 * q] = *(const f4*)(src + kb + 32 * q);
    }
    if (tid < 64) { mrow[tid] = -3.0e38f; lrow[tid] = 0.f; }

    float acc[4][8];
#pragma unroll
    for (int i = 0; i < 4; i++)
#pragma unroll
        for (int c = 0; c < 8; c++) acc[i][c] = 0.f;
    const float scale = 0.08838834764831845f;

    int ktmax = 2 * (qt + 1);
    for (int kt = 0; kt < ktmax; kt++) {
        __syncthreads();
#pragma unroll
        for (int p = 0; p < 4; p++) {
            int c = p * 8 + (tid >> 5);
            int kk = (tid & 31) * 4;
            size_t g = (size_t)(b * s + kt * 32 + c) * DD + h * DHH + kk;
            f4 kv = *(const f4*)(K + g);
            int ch = (kk >> 2) ^ (c >> 1);
            *(f4*)&Ks[c * 128 + ch * 4] = kv;
            *(f4*)&Vs[c][kk] = *(const f4*)(V + g);
        }
        __syncthreads();
        float sv[4][2];
#pragma unroll
        for (int i = 0; i < 4; i++) { sv[i][0] = 0.f; sv[i][1] = 0.f; }
        for (int kk = 0; kk < 128; kk += 4) {
            f4 qv[4];
#pragma unroll
            for (int i = 0; i < 4; i++) qv[i] = *(const f4*)&Qs[ty * 4 + i][kk];
#pragma unroll
            for (int j = 0; j < 2; j++) {
                int c = tx * 2 + j;
                int ch = (kk >> 2) ^ (c >> 1);
                f4 kv = *(const f4*)&Ks[c * 128 + ch * 4];
#pragma unroll
                for (int i = 0; i < 4; i++)
                    sv[i][j] += qv[i].x * kv.x + qv[i].y * kv.y +
                                qv[i].z * kv.z + qv[i].w * kv.w;
            }
        }
        float scl[4];
#pragma unroll
        for (int i = 0; i < 4; i++) {
            int r = ty * 4 + i;
            int igl = qt * 64 + r;
#pragma unroll
            for (int j = 0; j < 2; j++) {
                int jg = kt * 32 + tx * 2 + j;
                bool ok = (jg <= igl) && (mask[b * s + jg] > 0);
                sv[i][j] = ok ? sv[i][j] * scale : -1.0e9f;
            }
            float rmax = fmaxf(sv[i][0], sv[i][1]);
            rmax = fmaxf(rmax, __shfl_xor(rmax, 1));
            rmax = fmaxf(rmax, __shfl_xor(rmax, 2));
            rmax = fmaxf(rmax, __shfl_xor(rmax, 4));
            rmax = fmaxf(rmax, __shfl_xor(rmax, 8));
            float mold = mrow[r];
            float mnew = fmaxf(mold, rmax);
            float p0 = expf(sv[i][0] - mnew);
            float p1 = expf(sv[i][1] - mnew);
            float ps = p0 + p1;
            ps += __shfl_xor(ps, 1);
            ps += __shfl_xor(ps, 2);
            ps += __shfl_xor(ps, 4);
            ps += __shfl_xor(ps, 8);
            scl[i] = expf(mold - mnew);
            if (tx == 0) { mrow[r] = mnew; lrow[r] = lrow[r] * scl[i] + ps; }
            float2 pw; pw.x = p0; pw.y = p1;
            *(float2*)&Ps[r][tx * 2] = pw;
        }
        __syncthreads();
#pragma unroll
        for (int i = 0; i < 4; i++) {
            float sc = scl[i];
#pragma unroll
            for (int c = 0; c < 8; c++) acc[i][c] *= sc;
        }
        for (int jj = 0; jj < 32; jj += 4) {
            f4 pv[4];
#pragma unroll
            for (int i = 0; i < 4; i++) pv[i] = *(const f4*)&Ps[ty * 4 + i][jj];
#pragma unroll
            for (int j2 = 0; j2 < 4; j2++) {
                f4 va = *(const f4*)&Vs[jj + j2][tx * 4];
                f4 vb = *(const f4*)&Vs[jj + j2][64 + tx * 4];
#pragma unroll
                for (int i = 0; i < 4; i++) {
                    float p = (&pv[i].x)[j2];
                    acc[i][0] += p * va.x; acc[i][1] += p * va.y;
                    acc[i][2] += p * va.z; acc[i][3] += p * va.w;
                    acc[i][4] += p * vb.x; acc[i][5] += p * vb.y;
                    acc[i][6] += p * vb.z; acc[i][7] += p * vb.w;
                }
            }
        }
    }
    __syncthreads();
#pragma unroll
    for (int i = 0; i < 4; i++) {
        int r = ty * 4 + i;
        float linv = 1.0f / lrow[r];
        size_t ob = (size_t)(b * s + qt * 64 + r) * DD + h * DHH;
        ushort4 h1, l1, h2, l2;
        u16 *h1p = (u16*)&h1, *l1p = (u16*)&l1, *h2p = (u16*)&h2, *l2p = (u16*)&l2;
#pragma unroll
        for (int c = 0; c < 4; c++) {
            float v = acc[i][c] * linv;
            u16 hh = bf16rne(v);
            h1p[c] = hh; l1p[c] = bf16rne(v - bf16tof(hh));
            float v2 = acc[i][c + 4] * linv;
            u16 hh2 = bf16rne(v2);
            h2p[c] = hh2; l2p[c] = bf16rne(v2 - bf16tof(hh2));
        }
        *(ushort4*)&OH[ob + tx * 4] = h1;
        *(ushort4*)&OL[ob + tx * 4] = l1;
        *(ushort4*)&OH[ob + 64 + tx * 4] = h2;
        *(ushort4*)&OL[ob + 64 + tx * 4] = l2;
    }
}

// ---------------- prune scoring / selection ----------------
__global__ __launch_bounds__(256) void k_score(const float* __restrict__ Hb,
                                               const float* __restrict__ srow,
                                               float* __restrict__ sc) {
    int row = blockIdx.x;
    const float* xr = Hb + (size_t)row * DD;
    float ss = 0.f;
    for (int i = threadIdx.x; i < DD / 4; i += blockDim.x) {
        f4 a = ((const f4*)xr)[i];
        f4 w = ((const f4*)srow)[i];
        ss += a.x * w.x + a.y * w.y + a.z * w.z + a.w * w.w;
    }
    for (int o = 32; o > 0; o >>= 1) ss += __shfl_down(ss, o);
    __shared__ float red[4];
    int wid = threadIdx.x >> 6, lane = threadIdx.x & 63;
    if (lane == 0) red[wid] = ss;
    __syncthreads();
    if (threadIdx.x == 0) sc[row] = red[0] + red[1] + red[2] + red[3];
}

__global__ __launch_bounds__(256) void k_rank(const float* __restrict__ sc,
                                              int* __restrict__ flg, int s, int kk) {
    int b = blockIdx.x / s, i = blockIdx.x % s;
    const float* scb = sc + (size_t)b * s;
    float vi = scb[i];
    int cnt = 0;
    for (int j = threadIdx.x; j < s; j += 256) {
        float vj = scb[j];
        if (vj > vi || (vj == vi && j < i)) cnt++;
    }
    for (int o = 32; o > 0; o >>= 1) cnt += __shfl_down(cnt, o);
    __shared__ int red[4];
    int wid = threadIdx.x >> 6, lane = threadIdx.x & 63;
    if (lane == 0) red[wid] = cnt;
    __syncthreads();
    if (threadIdx.x == 0) flg[b * s + i] = ((red[0] + red[1] + red[2] + red[3]) < kk) ? 1 : 0;
}

__global__ void k_compact(const int* __restrict__ flg, int* __restrict__ idx, int s, int kk) {
    int b = blockIdx.x;
    if (threadIdx.x == 0) {
        int p = 0;
        for (int i = 0; i < s; i++)
            if (flg[b * s + i]) idx[b * kk + (p++)] = i;
    }
}

__global__ void k_gather(const float* __restrict__ Hin, const int* __restrict__ idx,
                         float* __restrict__ Hout, int s, int kk) {
    int row = blockIdx.x;
    int b = row / kk, p = row % kk;
    int i = idx[b * kk + p];
    const f4* src = (const f4*)(Hin + (size_t)(b * s + i) * DD);
    f4* dst = (f4*)(Hout + (size_t)row * DD);
    for (int t = threadIdx.x; t < DD / 4; t += blockDim.x) dst[t] = src[t];
}

__global__ void k_gather_mask(const int* __restrict__ Min, const int* __restrict__ idx,
                              int* __restrict__ Mout, int s, int kk) {
    int t = blockIdx.x * blockDim.x + threadIdx.x;
    if (t < BBATCH * kk) {
        int b = t / kk, p = t % kk;
        Mout[t] = Min[b * s + idx[b * kk + p]];
    }
}

// ---------------------------------------------------------------------------
extern "C" void kernel_launch(void* const* d_in, const int* in_sizes, int n_in,
                              void* d_out, int out_size, void* d_ws, size_t ws_size,
                              hipStream_t stream) {
    const int*   input_ids = (const int*)d_in[0];
    const int*   attn_mask = (const int*)d_in[1];
    const float* embed     = (const float*)d_in[2];
    const float* wq        = (const float*)d_in[3];
    const float* wk        = (const float*)d_in[4];
    const float* wv        = (const float*)d_in[5];
    const float* wo        = (const float*)d_in[6];
    const float* wg        = (const float*)d_in[7];
    const float* wu        = (const float*)d_in[8];
    const float* wd        = (const float*)d_in[9];
    const float* ln1       = (const float*)d_in[10];
    const float* ln2       = (const float*)d_in[11];
    const float* lnf       = (const float*)d_in[12];
    const float* lm_head   = (const float*)d_in[13];
    const float* scorer    = (const float*)d_in[14];

    float* ws = (float*)d_ws;
    const size_t R = (size_t)BBATCH * SSEQ * DD;        // 8,388,608 floats
    const size_t MISC_FLOATS = 2 * SSEQ * 64 + 5 * (size_t)BBATCH * SSEQ + 1024;
    const size_t NEED_A = (14 * R + MISC_FLOATS) * 4;   // ~471 MB
    const bool bigws = (ws_size >= NEED_A);

    float* H0 = ws;
    float* H1 = ws + R;
    float* CQ = ws + 2 * R;
    float* CK = ws + 3 * R;
    float* CV = ws + 4 * R;
    u16*   AH = (u16*)(ws + 5 * R);                     // [4096][2048] planes
    u16*   AL = AH + (size_t)4096 * DD;

    // tier A regions
    u16* FH  = (u16*)(ws + 6 * R);                      // [4096][8192]
    u16* FL  = FH + (size_t)4096 * FFF;                 // ends at 10R
    u16* WH1 = (u16*)(ws + 10 * R);                     // Wg hi [8192][2048]
    u16* WL1 = WH1 + (size_t)FFF * DD;                  // 11R
    u16* WH2 = (u16*)(ws + 12 * R);                     // Wu hi
    u16* WL2 = WH2 + (size_t)FFF * DD;                  // 13R
    u16* WDH = (u16*)(ws + 10 * R);                     // Wd hi [2048][8192] (reuse)
    u16* WDL = WDH + (size_t)DD * FFF;                  // 11R..12R

    // tier D regions (inside QKV space, free during MLP)
    u16* cWgH = (u16*)CQ;                      // [2048][2048] each
    u16* cWgL = cWgH + (size_t)2048 * DD;
    u16* cWuH = cWgL + (size_t)2048 * DD;
    u16* cWuL = cWuH + (size_t)2048 * DD;      // = ws+3R
    u16* cFH  = (u16*)(ws + 3 * R);            // [4096][2048]
    u16* cFL  = cFH + (size_t)4096 * 2048;     // = ws+4R
    u16* cWdH = (u16*)(ws + 4 * R);            // [2048][2048]
    u16* cWdL = cWdH + (size_t)2048 * DD;

    float* miscB = ws + (bigws ? 14 * R : 6 * R);
    float* COS = miscB;
    float* SIN = COS + SSEQ * 64;
    float* SC  = SIN + SSEQ * 64;
    int*   FLG = (int*)(SC + (size_t)BBATCH * SSEQ);
    int*   IDX = FLG + BBATCH * SSEQ;
    int*   M0  = IDX + BBATCH * SSEQ;
    int*   M1  = M0 + BBATCH * SSEQ;

    k_rope_table<<<(SSEQ * 64 + 255) / 256, 256, 0, stream>>>(COS, SIN);
    k_embed<<<BBATCH * SSEQ, 256, 0, stream>>>(input_ids, embed, H0);
    k_copy_int<<<(BBATCH * SSEQ + 255) / 256, 256, 0, stream>>>(attn_mask, M0, BBATCH * SSEQ);

    float* Hc = H0; float* Nc = H1;
    int*   Mc = M0; int*   Mt = M1;
    int s = SSEQ;

    for (int l = 0; l < LLAYERS; l++) {
        if (l == 1 || l == 2) {
            int pi = l - 1;
            int kk = s / 2;
            k_score<<<BBATCH * s, 256, 0, stream>>>(Hc, scorer + (size_t)pi * 2 * DD, SC);
            k_rank<<<BBATCH * s, 256, 0, stream>>>(SC, FLG, s, kk);
            k_compact<<<BBATCH, 64, 0, stream>>>(FLG, IDX, s, kk);
            k_gather<<<BBATCH * kk, 256, 0, stream>>>(Hc, IDX, Nc, s, kk);
            k_gather_mask<<<(BBATCH * kk + 255) / 256, 256, 0, stream>>>(Mc, IDX, Mt, s, kk);
            { float* t = Hc; Hc = Nc; Nc = t; }
            { int* t = Mc; Mc = Mt; Mt = t; }
            s = kk;
        }
        int rows = BBATCH * s;
        const bool hiP = (l < 2);   // 3-pass upstream of final prune
        const float* Wq = wq + (size_t)l * DD * DD;
        const float* Wk = wk + (size_t)l * DD * DD;
        const float* Wv = wv + (size_t)l * DD * DD;
        const float* Wo = wo + (size_t)l * DD * DD;
        const float* Wg = wg + (size_t)l * DD * FFF;
        const float* Wu = wu + (size_t)l * DD * FFF;
        const float* Wd = wd + (size_t)l * FFF * DD;
        const float* L1 = ln1 + (size_t)l * DD;
        const float* L2 = ln2 + (size_t)l * DD;

        u16* WtH = (u16*)Nc;                 // attn weight planes in idle Nc
        u16* WtL = WtH + (size_t)DD * DD;
        dim3 gWd(DD / 64, DD / 64);
        dim3 gG(DD / 128, rows / 128);

        // ---- attention path ----
        k_rmsnorm_cvt<<<rows, 256, 0, stream>>>(Hc, L1, AH, AL);
        k_cvt_w<<<gWd, 256, 0, stream>>>(Wq, WtH, WtL, DD, DD, 0);
        if (hiP) k_bgemm<3,0,0><<<gG,256,0,stream>>>(AH,AL,WtH,WtL,nullptr,nullptr,nullptr,CQ,nullptr,nullptr,rows,DD,DD);
        else     k_bgemm<1,0,0><<<gG,256,0,stream>>>(AH,AL,WtH,WtL,nullptr,nullptr,nullptr,CQ,nullptr,nullptr,rows,DD,DD);
        k_cvt_w<<<gWd, 256, 0, stream>>>(Wk, WtH, WtL, DD, DD, 0);
        if (hiP) k_bgemm<3,0,0><<<gG,256,0,stream>>>(AH,AL,WtH,WtL,nullptr,nullptr,nullptr,CK,nullptr,nullptr,rows,DD,DD);
        else     k_bgemm<1,0,0><<<gG,256,0,stream>>>(AH,AL,WtH,WtL,nullptr,nullptr,nullptr,CK,nullptr,nullptr,rows,DD,DD);
        k_cvt_w<<<gWd, 256, 0, stream>>>(Wv, WtH, WtL, DD, DD, 0);
        if (hiP) k_bgemm<3,0,0><<<gG,256,0,stream>>>(AH,AL,WtH,WtL,nullptr,nullptr,nullptr,CV,nullptr,nullptr,rows,DD,DD);
        else     k_bgemm<1,0,0><<<gG,256,0,stream>>>(AH,AL,WtH,WtL,nullptr,nullptr,nullptr,CV,nullptr,nullptr,rows,DD,DD);
        k_rope<<<rows * HH, 64, 0, stream>>>(CQ, CK, COS, SIN, s);
        k_attn<<<dim3(s / 64, BBATCH * HH), 256, 0, stream>>>(CQ, CK, CV, Mc, AH, AL, s);
        k_cvt_w<<<gWd, 256, 0, stream>>>(Wo, WtH, WtL, DD, DD, 0);
        if (hiP) k_bgemm<3,1,0><<<gG,256,0,stream>>>(AH,AL,WtH,WtL,nullptr,nullptr,Hc,Hc,nullptr,nullptr,rows,DD,DD);
        else     k_bgemm<1,1,0><<<gG,256,0,stream>>>(AH,AL,WtH,WtL,nullptr,nullptr,Hc,Hc,nullptr,nullptr,rows,DD,DD);

        // ---- MLP ----
        k_rmsnorm_cvt<<<rows, 256, 0, stream>>>(Hc, L2, AH, AL);
        if (bigws) {
            k_cvt_w<<<dim3(FFF / 64, DD / 64), 256, 0, stream>>>(Wg, WH1, WL1, DD, FFF, 0);
            k_cvt_w<<<dim3(FFF / 64, DD / 64), 256, 0, stream>>>(Wu, WH2, WL2, DD, FFF, 0);
            if (hiP) k_bgemm<3,0,1><<<dim3(FFF/128, rows/128),256,0,stream>>>(AH,AL,WH1,WL1,WH2,WL2,nullptr,nullptr,FH,FL,rows,FFF,DD);
            else     k_bgemm<1,0,1><<<dim3(FFF/128, rows/128),256,0,stream>>>(AH,AL,WH1,WL1,WH2,WL2,nullptr,nullptr,FH,FL,rows,FFF,DD);
            k_cvt_w<<<dim3(DD / 64, FFF / 64), 256, 0, stream>>>(Wd, WDH, WDL, FFF, DD, 0);
            if (hiP) k_bgemm<3,1,0><<<dim3(DD/128, rows/128),256,0,stream>>>(FH,FL,WDH,WDL,nullptr,nullptr,Hc,Hc,nullptr,nullptr,rows,DD,FFF);
            else     k_bgemm<1,1,0><<<dim3(DD/128, rows/128),256,0,stream>>>(FH,FL,WDH,WDL,nullptr,nullptr,Hc,Hc,nullptr,nullptr,rows,DD,FFF);
        } else {
            for (int ffc = 0; ffc < FFF; ffc += 2048) {
                k_cvt_w<<<dim3(2048 / 64, DD / 64), 256, 0, stream>>>(Wg, cWgH, cWgL, DD, FFF, ffc);
                k_cvt_w<<<dim3(2048 / 64, DD / 64), 256, 0, stream>>>(Wu, cWuH, cWuL, DD, FFF, ffc);
                if (hiP) k_bgemm<3,0,1><<<dim3(16, rows/128),256,0,stream>>>(AH,AL,cWgH,cWgL,cWuH,cWuL,nullptr,nullptr,cFH,cFL,rows,2048,DD);
                else     k_bgemm<1,0,1><<<dim3(16, rows/128),256,0,stream>>>(AH,AL,cWgH,cWgL,cWuH,cWuL,nullptr,nullptr,cFH,cFL,rows,2048,DD);
                k_cvt_w<<<dim3(DD / 64, 2048 / 64), 256, 0, stream>>>(Wd + (size_t)ffc * DD, cWdH, cWdL, 2048, DD, 0);
                // split-K accumulate: C = acc + C (first chunk adds residual Hc)
                if (hiP) k_bgemm<3,1,0><<<dim3(DD/128, rows/128),256,0,stream>>>(cFH,cFL,cWdH,cWdL,nullptr,nullptr,Hc,Hc,nullptr,nullptr,rows,DD,2048);
                else     k_bgemm<1,1,0><<<dim3(DD/128, rows/128),256,0,stream>>>(cFH,cFL,cWdH,cWdL,nullptr,nullptr,Hc,Hc,nullptr,nullptr,rows,DD,2048);
            }
        }
    }

    // final rmsnorm + lm_head (1-pass bf16, in-kernel convert; CQ region free)
    int rows = BBATCH * s;   // 1024
    k_rmsnorm<<<rows, 256, 0, stream>>>(Hc, lnf, CQ);
    k_mfma<1,0><<<dim3(VV / 128, rows / 128), 256, 0, stream>>>(
        CQ, lm_head, nullptr, (float*)d_out, rows, VV, DD);
}

// Round 5
// 7235.730 us; speedup vs baseline: 2.7810x; 1.0721x over previous
//
#include <hip/hip_runtime.h>
#include <math.h>

// ---------------------------------------------------------------------------
// SDTP forward, round 5.
// Changes vs r4: k_bgemm ported to the m97 structure (BK=32, linear LDS,
// global_load_lds width-16 staging, 2-barrier loop) -- zero staging VALU.
// lm_head now uses pre-converted bf16 weight plane + the same fast GEMM.
// Numerics identical to r4 (same bf16 values, same accumulation order).
// ---------------------------------------------------------------------------

#define DD 2048
#define HH 16
#define DHH 128
#define FFF 8192
#define BBATCH 2
#define SSEQ 2048
#define VV 32000
#define LLAYERS 4

typedef float4 f4;
typedef __attribute__((ext_vector_type(8))) short short8;
typedef __attribute__((ext_vector_type(4))) float f32x4;
typedef unsigned short u16;

__device__ inline u16 bf16rne(float x) {
    unsigned u = __float_as_uint(x);
    unsigned r = (u + 0x7FFFu + ((u >> 16) & 1u)) >> 16;
    return (u16)r;
}
__device__ inline float bf16tof(u16 h) {
    return __uint_as_float(((unsigned)h) << 16);
}

// async 16B global->LDS; lds dst must be wave-uniform base (HW adds lane*16)
__device__ __forceinline__ void gload16(const u16* g, u16* l) {
    __builtin_amdgcn_global_load_lds(
        (const __attribute__((address_space(1))) unsigned int*)g,
        (__attribute__((address_space(3))) unsigned int*)l, 16, 0, 0);
}

// ---------------- embedding / copies ----------------
__global__ void k_embed(const int* __restrict__ ids, const float* __restrict__ emb,
                        float* __restrict__ out) {
    int row = blockIdx.x;
    int id  = ids[row];
    const f4* src = (const f4*)(emb + (size_t)id * DD);
    f4*       dst = (f4*)(out + (size_t)row * DD);
    for (int i = threadIdx.x; i < DD / 4; i += blockDim.x) dst[i] = src[i];
}

__global__ void k_copy_int(const int* __restrict__ src, int* __restrict__ dst, int n) {
    int i = blockIdx.x * blockDim.x + threadIdx.x;
    if (i < n) dst[i] = src[i];
}

// ---------------- rmsnorm -> bf16 hi/lo planes ----------------
__global__ __launch_bounds__(256) void k_rmsnorm_cvt(const float* __restrict__ x,
                                                     const float* __restrict__ w,
                                                     u16* __restrict__ OH,
                                                     u16* __restrict__ OL) {
    int row = blockIdx.x;
    const float* xr = x + (size_t)row * DD;
    float ss = 0.f;
    for (int i = threadIdx.x; i < DD / 4; i += blockDim.x) {
        f4 v = ((const f4*)xr)[i];
        ss += v.x * v.x + v.y * v.y + v.z * v.z + v.w * v.w;
    }
    for (int o = 32; o > 0; o >>= 1) ss += __shfl_down(ss, o);
    __shared__ float red[4];
    int wid = threadIdx.x >> 6, lane = threadIdx.x & 63;
    if (lane == 0) red[wid] = ss;
    __syncthreads();
    float tot = red[0] + red[1] + red[2] + red[3];
    float inv = 1.0f / sqrtf(tot / (float)DD + 1e-6f);
    for (int i = threadIdx.x; i < DD / 4; i += blockDim.x) {
        f4 v = ((const f4*)xr)[i];
        f4 wv = ((const f4*)w)[i];
        float o[4];
        o[0] = v.x * wv.x * inv; o[1] = v.y * wv.y * inv;
        o[2] = v.z * wv.z * inv; o[3] = v.w * wv.w * inv;
        ushort4 hv, lv;
        u16* hp = (u16*)&hv; u16* lp = (u16*)&lv;
#pragma unroll
        for (int j = 0; j < 4; j++) {
            u16 h = bf16rne(o[j]);
            hp[j] = h;
            lp[j] = bf16rne(o[j] - bf16tof(h));
        }
        *(ushort4*)&OH[(size_t)row * DD + i * 4] = hv;
        *(ushort4*)&OL[(size_t)row * DD + i * 4] = lv;
    }
}

// ---------------- weight transpose+convert: W[K][N] -> planes [n][K] -------
// grid (nch/64, K/64); WtH/WtL row-major, ld K; n LOCAL to chunk at nc0.
__global__ __launch_bounds__(256) void k_cvt_w(const float* __restrict__ W,
                                               u16* __restrict__ WtH,
                                               u16* __restrict__ WtL,
                                               int K, int N, int nc0, int writeLo) {
    __shared__ float T[64][65];
    int tid = threadIdx.x;
    int n0g = nc0 + blockIdx.x * 64;
    int k0  = blockIdx.y * 64;
#pragma unroll
    for (int it = 0; it < 4; it++) {
        int r = it * 16 + (tid >> 4);
        int c4 = (tid & 15) * 4;
        f4 v = *(const f4*)(W + (size_t)(k0 + r) * N + n0g + c4);
        T[r][c4 + 0] = v.x; T[r][c4 + 1] = v.y;
        T[r][c4 + 2] = v.z; T[r][c4 + 3] = v.w;
    }
    __syncthreads();
    int nl = tid >> 2;
    int ks = (tid & 3) * 16;
    u16 hi[16], lo[16];
#pragma unroll
    for (int j = 0; j < 16; j++) {
        float v = T[ks + j][nl];
        u16 h = bf16rne(v);
        hi[j] = h;
        lo[j] = bf16rne(v - bf16tof(h));
    }
    size_t base = (size_t)(blockIdx.x * 64 + nl) * K + k0 + ks;
    *(short8*)&WtH[base]     = *(short8*)&hi[0];
    *(short8*)&WtH[base + 8] = *(short8*)&hi[8];
    if (writeLo) {
        *(short8*)&WtL[base]     = *(short8*)&lo[0];
        *(short8*)&WtL[base + 8] = *(short8*)&lo[8];
    }
}

// ---------------- bf16 MFMA GEMM, m97 structure ----------------
// A planes [M][K]; B planes [n][K]. Phases: 0 Ah*Bh, 1 Ah*Bl, 2 Al*Bh.
// Block 128x128, BK=32, 4 waves (2x2), 16x16x32 MFMA, linear LDS [128][32],
// global_load_lds width-16 staging (wave-uniform LDS base + lane*16).
template <int PASSES, int RES, int DUAL>
__global__ __launch_bounds__(256, 2) void k_bgemm(const u16* __restrict__ AH,
                                                  const u16* __restrict__ AL,
                                                  const u16* __restrict__ B1H,
                                                  const u16* __restrict__ B1L,
                                                  const u16* __restrict__ B2H,
                                                  const u16* __restrict__ B2L,
                                                  const float* __restrict__ Rsrc,
                                                  float* __restrict__ C,
                                                  u16* __restrict__ OH,
                                                  u16* __restrict__ OL,
                                                  int M, int ldC, int K) {
    constexpr int NW = DUAL ? 2 : 1;
    __shared__ u16 As[128 * 32];
    __shared__ u16 Bs[NW][128 * 32];
    int tid = threadIdx.x;
    int m0 = blockIdx.y * 128, n0 = blockIdx.x * 128;
    int lane = tid & 63, w = tid >> 6;
    int wm = w >> 1, wn = w & 1;
    int lr = lane & 15, lq = lane >> 4;
    int grow = lane >> 2;            // 0..15: row within 16-row load group
    int gcol = (lane & 3) * 8;       // bf16 col within 32-wide K tile

    f32x4 acc[NW][4][4];
#pragma unroll
    for (int u = 0; u < NW; u++)
#pragma unroll
        for (int i = 0; i < 4; i++)
#pragma unroll
            for (int j = 0; j < 4; j++)
#pragma unroll
                for (int r = 0; r < 4; r++) acc[u][i][j][r] = 0.f;

    const int KT = PASSES * K;
    for (int kb = 0; kb < KT; kb += 32) {
        int p  = (PASSES > 1) ? ((kb >= 2 * K) ? 2 : ((kb >= K) ? 1 : 0)) : 0;
        int ks = kb - p * K;
        const u16* Ab = ((p == 2) ? AL  : AH)  + (size_t)(m0 + w * 32) * K + ks;
        const u16* Bb = ((p == 1) ? B1L : B1H) + (size_t)(n0 + w * 32) * K + ks;
        __syncthreads();
        gload16(Ab + (size_t)grow * K + gcol,        &As[w * 1024]);
        gload16(Ab + (size_t)(grow + 16) * K + gcol, &As[w * 1024 + 512]);
        gload16(Bb + (size_t)grow * K + gcol,        &Bs[0][w * 1024]);
        gload16(Bb + (size_t)(grow + 16) * K + gcol, &Bs[0][w * 1024 + 512]);
        if constexpr (DUAL) {
            const u16* B2b = ((p == 1) ? B2L : B2H) + (size_t)(n0 + w * 32) * K + ks;
            gload16(B2b + (size_t)grow * K + gcol,        &Bs[1][w * 1024]);
            gload16(B2b + (size_t)(grow + 16) * K + gcol, &Bs[1][w * 1024 + 512]);
        }
        __syncthreads();   // compiler drains vmcnt before barrier -> tiles ready
        short8 a[4];
#pragma unroll
        for (int i = 0; i < 4; i++)
            a[i] = *(const short8*)&As[(wm * 64 + i * 16 + lr) * 32 + lq * 8];
#pragma unroll
        for (int u = 0; u < NW; u++) {
#pragma unroll
            for (int j = 0; j < 4; j++) {
                short8 b = *(const short8*)&Bs[u][(wn * 64 + j * 16 + lr) * 32 + lq * 8];
#pragma unroll
                for (int i = 0; i < 4; i++)
                    acc[u][i][j] = __builtin_amdgcn_mfma_f32_16x16x32_bf16(
                        a[i], b, acc[u][i][j], 0, 0, 0);
            }
        }
    }
    // epilogue: C/D layout col = lane&15, row = (lane>>4)*4 + reg
#pragma unroll
    for (int i = 0; i < 4; i++) {
#pragma unroll
        for (int j = 0; j < 4; j++) {
            int gm = m0 + wm * 64 + i * 16 + lq * 4;
            int gn = n0 + wn * 64 + j * 16 + lr;
#pragma unroll
            for (int r = 0; r < 4; r++) {
                size_t off = (size_t)(gm + r) * ldC + gn;
                if constexpr (DUAL) {
                    float g = acc[0][i][j][r], uu = acc[1][i][j][r];
                    float v = g / (1.0f + expf(-g)) * uu;
                    u16 h = bf16rne(v);
                    OH[off] = h;
                    OL[off] = bf16rne(v - bf16tof(h));
                } else {
                    float v = acc[0][i][j][r];
                    if constexpr (RES) v += Rsrc[off];
                    C[off] = v;
                }
            }
        }
    }
}

// ---------------- RoPE ----------------
__global__ void k_rope_table(float* __restrict__ cosT, float* __restrict__ sinT) {
    int idx = blockIdx.x * blockDim.x + threadIdx.x;
    if (idx >= SSEQ * 64) return;
    int pos = idx >> 6, d = idx & 63;
    float p   = (float)pow(10000.0, (double)d * (1.0 / 64.0));
    float inv = 1.0f / p;
    float ang = (float)pos * inv;
    cosT[idx] = (float)cos((double)ang);
    sinT[idx] = (float)sin((double)ang);
}

__global__ void k_rope(float* __restrict__ Cq, float* __restrict__ Ck,
                       const float* __restrict__ cosT, const float* __restrict__ sinT,
                       int s) {
    int bi = blockIdx.x;
    int h = bi % HH;
    int i = (bi / HH) % s;
    size_t base = (size_t)(bi / HH) * DD + h * DHH;
    int d = threadIdx.x;
    float c  = cosT[i * 64 + d];
    float sn = sinT[i * 64 + d];
    float x1 = Cq[base + d], x2 = Cq[base + 64 + d];
    Cq[base + d]      = x1 * c - x2 * sn;
    Cq[base + 64 + d] = x1 * sn + x2 * c;
    x1 = Ck[base + d]; x2 = Ck[base + 64 + d];
    Ck[base + d]      = x1 * c - x2 * sn;
    Ck[base + 64 + d] = x1 * sn + x2 * c;
}

// ---------------- flash attention fp32 -> bf16x2 output planes ---------------
__global__ __launch_bounds__(256, 2) void k_attn(const float* __restrict__ Q,
                                                 const float* __restrict__ K,
                                                 const float* __restrict__ V,
                                                 const int* __restrict__ mask,
                                                 u16* __restrict__ OH,
                                                 u16* __restrict__ OL, int s) {
    int qt = blockIdx.x, bh = blockIdx.y;
    int h = bh & (HH - 1), b = bh >> 4;
    __shared__ float Qs[64][132];
    __shared__ float Ks[32 * 128];
    __shared__ float Vs[32][132];
    __shared__ float Ps[64][36];
    __shared__ float mrow[64], lrow[64];
    int tid = threadIdx.x;
    int tx = tid & 15, ty = tid >> 4;

#pragma unroll
    for (int p = 0; p < 2; p++) {
        int r = p * 32 + (tid >> 3);
        int kb = (tid & 7) * 4;
        const float* src = Q + (size_t)(b * s + qt * 64 + r) * DD + h * DHH;
#pragma unroll
        for (int q = 0; q < 4; q++)
            *(f4*)&Qs[r][kb + 32 * q] = *(const f4*)(src + kb + 32 * q);
    }
    if (tid < 64) { mrow[tid] = -3.0e38f; lrow[tid] = 0.f; }

    float acc[4][8];
#pragma unroll
    for (int i = 0; i < 4; i++)
#pragma unroll
        for (int c = 0; c < 8; c++) acc[i][c] = 0.f;
    const float scale = 0.08838834764831845f;

    int ktmax = 2 * (qt + 1);
    for (int kt = 0; kt < ktmax; kt++) {
        __syncthreads();
#pragma unroll
        for (int p = 0; p < 4; p++) {
            int c = p * 8 + (tid >> 5);
            int kk = (tid & 31) * 4;
            size_t g = (size_t)(b * s + kt * 32 + c) * DD + h * DHH + kk;
            f4 kv = *(const f4*)(K + g);
            int ch = (kk >> 2) ^ (c >> 1);
            *(f4*)&Ks[c * 128 + ch * 4] = kv;
            *(f4*)&Vs[c][kk] = *(const f4*)(V + g);
        }
        __syncthreads();
        float sv[4][2];
#pragma unroll
        for (int i = 0; i < 4; i++) { sv[i][0] = 0.f; sv[i][1] = 0.f; }
        for (int kk = 0; kk < 128; kk += 4) {
            f4 qv[4];
#pragma unroll
            for (int i = 0; i < 4; i++) qv[i] = *(const f4*)&Qs[ty * 4 + i][kk];
#pragma unroll
            for (int j = 0; j < 2; j++) {
                int c = tx * 2 + j;
                int ch = (kk >> 2) ^ (c >> 1);
                f4 kv = *(const f4*)&Ks[c * 128 + ch * 4];
#pragma unroll
                for (int i = 0; i < 4; i++)
                    sv[i][j] += qv[i].x * kv.x + qv[i].y * kv.y +
                                qv[i].z * kv.z + qv[i].w * kv.w;
            }
        }
        float scl[4];
#pragma unroll
        for (int i = 0; i < 4; i++) {
            int r = ty * 4 + i;
            int igl = qt * 64 + r;
#pragma unroll
            for (int j = 0; j < 2; j++) {
                int jg = kt * 32 + tx * 2 + j;
                bool ok = (jg <= igl) && (mask[b * s + jg] > 0);
                sv[i][j] = ok ? sv[i][j] * scale : -1.0e9f;
            }
            float rmax = fmaxf(sv[i][0], sv[i][1]);
            rmax = fmaxf(rmax, __shfl_xor(rmax, 1));
            rmax = fmaxf(rmax, __shfl_xor(rmax, 2));
            rmax = fmaxf(rmax, __shfl_xor(rmax, 4));
            rmax = fmaxf(rmax, __shfl_xor(rmax, 8));
            float mold = mrow[r];
            float mnew = fmaxf(mold, rmax);
            float p0 = expf(sv[i][0] - mnew);
            float p1 = expf(sv[i][1] - mnew);
            float ps = p0 + p1;
            ps += __shfl_xor(ps, 1);
            ps += __shfl_xor(ps, 2);
            ps += __shfl_xor(ps, 4);
            ps += __shfl_xor(ps, 8);
            scl[i] = expf(mold - mnew);
            if (tx == 0) { mrow[r] = mnew; lrow[r] = lrow[r] * scl[i] + ps; }
            float2 pw; pw.x = p0; pw.y = p1;
            *(float2*)&Ps[r][tx * 2] = pw;
        }
        __syncthreads();
#pragma unroll
        for (int i = 0; i < 4; i++) {
            float sc = scl[i];
#pragma unroll
            for (int c = 0; c < 8; c++) acc[i][c] *= sc;
        }
        for (int jj = 0; jj < 32; jj += 4) {
            f4 pv[4];
#pragma unroll
            for (int i = 0; i < 4; i++) pv[i] = *(const f4*)&Ps[ty * 4 + i][jj];
#pragma unroll
            for (int j2 = 0; j2 < 4; j2++) {
                f4 va = *(const f4*)&Vs[jj + j2][tx * 4];
                f4 vb = *(const f4*)&Vs[jj + j2][64 + tx * 4];
#pragma unroll
                for (int i = 0; i < 4; i++) {
                    float p = (&pv[i].x)[j2];
                    acc[i][0] += p * va.x; acc[i][1] += p * va.y;
                    acc[i][2] += p * va.z; acc[i][3] += p * va.w;
                    acc[i][4] += p * vb.x; acc[i][5] += p * vb.y;
                    acc[i][6] += p * vb.z; acc[i][7] += p * vb.w;
                }
            }
        }
    }
    __syncthreads();
#pragma unroll
    for (int i = 0; i < 4; i++) {
        int r = ty * 4 + i;
        float linv = 1.0f / lrow[r];
        size_t ob = (size_t)(b * s + qt * 64 + r) * DD + h * DHH;
        ushort4 h1, l1, h2, l2;
        u16 *h1p = (u16*)&h1, *l1p = (u16*)&l1, *h2p = (u16*)&h2, *l2p = (u16*)&l2;
#pragma unroll
        for (int c = 0; c < 4; c++) {
            float v = acc[i][c] * linv;
            u16 hh = bf16rne(v);
            h1p[c] = hh; l1p[c] = bf16rne(v - bf16tof(hh));
            float v2 = acc[i][c + 4] * linv;
            u16 hh2 = bf16rne(v2);
            h2p[c] = hh2; l2p[c] = bf16rne(v2 - bf16tof(hh2));
        }
        *(ushort4*)&OH[ob + tx * 4] = h1;
        *(ushort4*)&OL[ob + tx * 4] = l1;
        *(ushort4*)&OH[ob + 64 + tx * 4] = h2;
        *(ushort4*)&OL[ob + 64 + tx * 4] = l2;
    }
}

// ---------------- prune scoring / selection ----------------
__global__ __launch_bounds__(256) void k_score(const float* __restrict__ Hb,
                                               const float* __restrict__ srow,
                                               float* __restrict__ sc) {
    int row = blockIdx.x;
    const float* xr = Hb + (size_t)row * DD;
    float ss = 0.f;
    for (int i = threadIdx.x; i < DD / 4; i += blockDim.x) {
        f4 a = ((const f4*)xr)[i];
        f4 w = ((const f4*)srow)[i];
        ss += a.x * w.x + a.y * w.y + a.z * w.z + a.w * w.w;
    }
    for (int o = 32; o > 0; o >>= 1) ss += __shfl_down(ss, o);
    __shared__ float red[4];
    int wid = threadIdx.x >> 6, lane = threadIdx.x & 63;
    if (lane == 0) red[wid] = ss;
    __syncthreads();
    if (threadIdx.x == 0) sc[row] = red[0] + red[1] + red[2] + red[3];
}

__global__ __launch_bounds__(256) void k_rank(const float* __restrict__ sc,
                                              int* __restrict__ flg, int s, int kk) {
    int b = blockIdx.x / s, i = blockIdx.x % s;
    const float* scb = sc + (size_t)b * s;
    float vi = scb[i];
    int cnt = 0;
    for (int j = threadIdx.x; j < s; j += 256) {
        float vj = scb[j];
        if (vj > vi || (vj == vi && j < i)) cnt++;
    }
    for (int o = 32; o > 0; o >>= 1) cnt += __shfl_down(cnt, o);
    __shared__ int red[4];
    int wid = threadIdx.x >> 6, lane = threadIdx.x & 63;
    if (lane == 0) red[wid] = cnt;
    __syncthreads();
    if (threadIdx.x == 0) flg[b * s + i] = ((red[0] + red[1] + red[2] + red[3]) < kk) ? 1 : 0;
}

__global__ void k_compact(const int* __restrict__ flg, int* __restrict__ idx, int s, int kk) {
    int b = blockIdx.x;
    if (threadIdx.x == 0) {
        int p = 0;
        for (int i = 0; i < s; i++)
            if (flg[b * s + i]) idx[b * kk + (p++)] = i;
    }
}

__global__ void k_gather(const float* __restrict__ Hin, const int* __restrict__ idx,
                         float* __restrict__ Hout, int s, int kk) {
    int row = blockIdx.x;
    int b = row / kk, p = row % kk;
    int i = idx[b * kk + p];
    const f4* src = (const f4*)(Hin + (size_t)(b * s + i) * DD);
    f4* dst = (f4*)(Hout + (size_t)row * DD);
    for (int t = threadIdx.x; t < DD / 4; t += blockDim.x) dst[t] = src[t];
}

__global__ void k_gather_mask(const int* __restrict__ Min, const int* __restrict__ idx,
                              int* __restrict__ Mout, int s, int kk) {
    int t = blockIdx.x * blockDim.x + threadIdx.x;
    if (t < BBATCH * kk) {
        int b = t / kk, p = t % kk;
        Mout[t] = Min[b * s + idx[b * kk + p]];
    }
}

// ---------------------------------------------------------------------------
extern "C" void kernel_launch(void* const* d_in, const int* in_sizes, int n_in,
                              void* d_out, int out_size, void* d_ws, size_t ws_size,
                              hipStream_t stream) {
    const int*   input_ids = (const int*)d_in[0];
    const int*   attn_mask = (const int*)d_in[1];
    const float* embed     = (const float*)d_in[2];
    const float* wq        = (const float*)d_in[3];
    const float* wk        = (const float*)d_in[4];
    const float* wv        = (const float*)d_in[5];
    const float* wo        = (const float*)d_in[6];
    const float* wg        = (const float*)d_in[7];
    const float* wu        = (const float*)d_in[8];
    const float* wd        = (const float*)d_in[9];
    const float* ln1       = (const float*)d_in[10];
    const float* ln2       = (const float*)d_in[11];
    const float* lnf       = (const float*)d_in[12];
    const float* lm_head   = (const float*)d_in[13];
    const float* scorer    = (const float*)d_in[14];

    float* ws = (float*)d_ws;
    const size_t R = (size_t)BBATCH * SSEQ * DD;        // 8,388,608 floats
    const size_t MISC_FLOATS = 2 * SSEQ * 64 + 5 * (size_t)BBATCH * SSEQ + 1024;
    const size_t NEED_A = (14 * R + MISC_FLOATS) * 4;   // ~471 MB
    const bool bigws = (ws_size >= NEED_A);

    float* H0 = ws;
    float* H1 = ws + R;
    float* CQ = ws + 2 * R;
    float* CK = ws + 3 * R;
    float* CV = ws + 4 * R;
    u16*   AH = (u16*)(ws + 5 * R);                     // [4096][2048] planes
    u16*   AL = AH + (size_t)4096 * DD;

    // tier A regions
    u16* FH  = (u16*)(ws + 6 * R);                      // [4096][8192]
    u16* FL  = FH + (size_t)4096 * FFF;                 // ends at 10R
    u16* WH1 = (u16*)(ws + 10 * R);                     // Wg hi [8192][2048]
    u16* WL1 = WH1 + (size_t)FFF * DD;                  // 11R
    u16* WH2 = (u16*)(ws + 12 * R);                     // Wu hi
    u16* WL2 = WH2 + (size_t)FFF * DD;                  // 13R
    u16* WDH = (u16*)(ws + 10 * R);                     // Wd hi [2048][8192] (reuse)
    u16* WDL = WDH + (size_t)DD * FFF;                  // 11R..12R

    // tier D regions (inside QKV space, free during MLP)
    u16* cWgH = (u16*)CQ;
    u16* cWgL = cWgH + (size_t)2048 * DD;
    u16* cWuH = cWgL + (size_t)2048 * DD;
    u16* cWuL = cWuH + (size_t)2048 * DD;
    u16* cFH  = (u16*)(ws + 3 * R);
    u16* cFL  = cFH + (size_t)4096 * 2048;
    u16* cWdH = (u16*)(ws + 4 * R);
    u16* cWdL = cWdH + (size_t)2048 * DD;

    float* miscB = ws + (bigws ? 14 * R : 6 * R);
    float* COS = miscB;
    float* SIN = COS + SSEQ * 64;
    float* SC  = SIN + SSEQ * 64;
    int*   FLG = (int*)(SC + (size_t)BBATCH * SSEQ);
    int*   IDX = FLG + BBATCH * SSEQ;
    int*   M0  = IDX + BBATCH * SSEQ;
    int*   M1  = M0 + BBATCH * SSEQ;

    k_rope_table<<<(SSEQ * 64 + 255) / 256, 256, 0, stream>>>(COS, SIN);
    k_embed<<<BBATCH * SSEQ, 256, 0, stream>>>(input_ids, embed, H0);
    k_copy_int<<<(BBATCH * SSEQ + 255) / 256, 256, 0, stream>>>(attn_mask, M0, BBATCH * SSEQ);

    float* Hc = H0; float* Nc = H1;
    int*   Mc = M0; int*   Mt = M1;
    int s = SSEQ;

    for (int l = 0; l < LLAYERS; l++) {
        if (l == 1 || l == 2) {
            int pi = l - 1;
            int kk = s / 2;
            k_score<<<BBATCH * s, 256, 0, stream>>>(Hc, scorer + (size_t)pi * 2 * DD, SC);
            k_rank<<<BBATCH * s, 256, 0, stream>>>(SC, FLG, s, kk);
            k_compact<<<BBATCH, 64, 0, stream>>>(FLG, IDX, s, kk);
            k_gather<<<BBATCH * kk, 256, 0, stream>>>(Hc, IDX, Nc, s, kk);
            k_gather_mask<<<(BBATCH * kk + 255) / 256, 256, 0, stream>>>(Mc, IDX, Mt, s, kk);
            { float* t = Hc; Hc = Nc; Nc = t; }
            { int* t = Mc; Mc = Mt; Mt = t; }
            s = kk;
        }
        int rows = BBATCH * s;
        const bool hiP = (l < 2);   // 3-pass upstream of final prune
        const int wlo = hiP ? 1 : 0;
        const float* Wq = wq + (size_t)l * DD * DD;
        const float* Wk = wk + (size_t)l * DD * DD;
        const float* Wv = wv + (size_t)l * DD * DD;
        const float* Wo = wo + (size_t)l * DD * DD;
        const float* Wg = wg + (size_t)l * DD * FFF;
        const float* Wu = wu + (size_t)l * DD * FFF;
        const float* Wd = wd + (size_t)l * FFF * DD;
        const float* L1 = ln1 + (size_t)l * DD;
        const float* L2 = ln2 + (size_t)l * DD;

        u16* WtH = (u16*)Nc;                 // attn weight planes in idle Nc
        u16* WtL = WtH + (size_t)DD * DD;
        dim3 gWd(DD / 64, DD / 64);
        dim3 gG(DD / 128, rows / 128);

        // ---- attention path ----
        k_rmsnorm_cvt<<<rows, 256, 0, stream>>>(Hc, L1, AH, AL);
        k_cvt_w<<<gWd, 256, 0, stream>>>(Wq, WtH, WtL, DD, DD, 0, wlo);
        if (hiP) k_bgemm<3,0,0><<<gG,256,0,stream>>>(AH,AL,WtH,WtL,nullptr,nullptr,nullptr,CQ,nullptr,nullptr,rows,DD,DD);
        else     k_bgemm<1,0,0><<<gG,256,0,stream>>>(AH,AL,WtH,WtL,nullptr,nullptr,nullptr,CQ,nullptr,nullptr,rows,DD,DD);
        k_cvt_w<<<gWd, 256, 0, stream>>>(Wk, WtH, WtL, DD, DD, 0, wlo);
        if (hiP) k_bgemm<3,0,0><<<gG,256,0,stream>>>(AH,AL,WtH,WtL,nullptr,nullptr,nullptr,CK,nullptr,nullptr,rows,DD,DD);
        else     k_bgemm<1,0,0><<<gG,256,0,stream>>>(AH,AL,WtH,WtL,nullptr,nullptr,nullptr,CK,nullptr,nullptr,rows,DD,DD);
        k_cvt_w<<<gWd, 256, 0, stream>>>(Wv, WtH, WtL, DD, DD, 0, wlo);
        if (hiP) k_bgemm<3,0,0><<<gG,256,0,stream>>>(AH,AL,WtH,WtL,nullptr,nullptr,nullptr,CV,nullptr,nullptr,rows,DD,DD);
        else     k_bgemm<1,0,0><<<gG,256,0,stream>>>(AH,AL,WtH,WtL,nullptr,nullptr,nullptr,CV,nullptr,nullptr,rows,DD,DD);
        k_rope<<<rows * HH, 64, 0, stream>>>(CQ, CK, COS, SIN, s);
        k_attn<<<dim3(s / 64, BBATCH * HH), 256, 0, stream>>>(CQ, CK, CV, Mc, AH, AL, s);
        k_cvt_w<<<gWd, 256, 0, stream>>>(Wo, WtH, WtL, DD, DD, 0, wlo);
        if (hiP) k_bgemm<3,1,0><<<gG,256,0,stream>>>(AH,AL,WtH,WtL,nullptr,nullptr,Hc,Hc,nullptr,nullptr,rows,DD,DD);
        else     k_bgemm<1,1,0><<<gG,256,0,stream>>>(AH,AL,WtH,WtL,nullptr,nullptr,Hc,Hc,nullptr,nullptr,rows,DD,DD);

        // ---- MLP ----
        k_rmsnorm_cvt<<<rows, 256, 0, stream>>>(Hc, L2, AH, AL);
        if (bigws) {
            k_cvt_w<<<dim3(FFF / 64, DD / 64), 256, 0, stream>>>(Wg, WH1, WL1, DD, FFF, 0, wlo);
            k_cvt_w<<<dim3(FFF / 64, DD / 64), 256, 0, stream>>>(Wu, WH2, WL2, DD, FFF, 0, wlo);
            if (hiP) k_bgemm<3,0,1><<<dim3(FFF/128, rows/128),256,0,stream>>>(AH,AL,WH1,WL1,WH2,WL2,nullptr,nullptr,FH,FL,rows,FFF,DD);
            else     k_bgemm<1,0,1><<<dim3(FFF/128, rows/128),256,0,stream>>>(AH,AL,WH1,WL1,WH2,WL2,nullptr,nullptr,FH,FL,rows,FFF,DD);
            k_cvt_w<<<dim3(DD / 64, FFF / 64), 256, 0, stream>>>(Wd, WDH, WDL, FFF, DD, 0, wlo);
            if (hiP) k_bgemm<3,1,0><<<dim3(DD/128, rows/128),256,0,stream>>>(FH,FL,WDH,WDL,nullptr,nullptr,Hc,Hc,nullptr,nullptr,rows,DD,FFF);
            else     k_bgemm<1,1,0><<<dim3(DD/128, rows/128),256,0,stream>>>(FH,FL,WDH,WDL,nullptr,nullptr,Hc,Hc,nullptr,nullptr,rows,DD,FFF);
        } else {
            for (int ffc = 0; ffc < FFF; ffc += 2048) {
                k_cvt_w<<<dim3(2048 / 64, DD / 64), 256, 0, stream>>>(Wg, cWgH, cWgL, DD, FFF, ffc, wlo);
                k_cvt_w<<<dim3(2048 / 64, DD / 64), 256, 0, stream>>>(Wu, cWuH, cWuL, DD, FFF, ffc, wlo);
                if (hiP) k_bgemm<3,0,1><<<dim3(16, rows/128),256,0,stream>>>(AH,AL,cWgH,cWgL,cWuH,cWuL,nullptr,nullptr,cFH,cFL,rows,2048,DD);
                else     k_bgemm<1,0,1><<<dim3(16, rows/128),256,0,stream>>>(AH,AL,cWgH,cWgL,cWuH,cWuL,nullptr,nullptr,cFH,cFL,rows,2048,DD);
                k_cvt_w<<<dim3(DD / 64, 2048 / 64), 256, 0, stream>>>(Wd + (size_t)ffc * DD, cWdH, cWdL, 2048, DD, 0, wlo);
                if (hiP) k_bgemm<3,1,0><<<dim3(DD/128, rows/128),256,0,stream>>>(cFH,cFL,cWdH,cWdL,nullptr,nullptr,Hc,Hc,nullptr,nullptr,rows,DD,2048);
                else     k_bgemm<1,1,0><<<dim3(DD/128, rows/128),256,0,stream>>>(cFH,cFL,cWdH,cWdL,nullptr,nullptr,Hc,Hc,nullptr,nullptr,rows,DD,2048);
            }
        }
    }

    // ---- final rmsnorm + lm_head (1-pass bf16, pre-converted weight plane) --
    int rows = BBATCH * s;   // 1024
    u16* AHf = (u16*)Nc;                       // Nc free: A planes for lm_head
    u16* ALf = AHf + (size_t)rows * DD;
    u16* LmH = bigws ? (u16*)(ws + 6 * R)      // FH region (free post-MLP)
                     : (u16*)CQ;               // 2R..6R region (free)
    k_rmsnorm_cvt<<<rows, 256, 0, stream>>>(Hc, lnf, AHf, ALf);
    k_cvt_w<<<dim3(VV / 64, DD / 64), 256, 0, stream>>>(lm_head, LmH, LmH, DD, VV, 0, 0);
    k_bgemm<1,0,0><<<dim3(VV / 128, rows / 128), 256, 0, stream>>>(
        AHf, ALf, LmH, LmH, nullptr, nullptr, nullptr, (float*)d_out,
        nullptr, nullptr, rows, VV, DD);
}

// Round 6
// 5590.216 us; speedup vs baseline: 3.5996x; 1.2944x over previous
//
#include <hip/hip_runtime.h>
#include <math.h>

// ---------------------------------------------------------------------------
// SDTP forward, round 6.
// vs r5: (1) MFMA flash attention (bf16x2 3-pass @L0/L1, 1-pass @L2/L3) with
// pre-converted Q/K planes and granule-swizzled V^T planes; (2) fused QKV
// projection (single GEMM, N=6144). GEMMs keep the m97 structure.
// ---------------------------------------------------------------------------

#define DD 2048
#define HH 16
#define DHH 128
#define FFF 8192
#define BBATCH 2
#define SSEQ 2048
#define VV 32000
#define LLAYERS 4

typedef float4 f4;
typedef __attribute__((ext_vector_type(8))) short short8;
typedef __attribute__((ext_vector_type(4))) float f32x4;
typedef unsigned short u16;

__device__ inline u16 bf16rne(float x) {
    unsigned u = __float_as_uint(x);
    unsigned r = (u + 0x7FFFu + ((u >> 16) & 1u)) >> 16;
    return (u16)r;
}
__device__ inline float bf16tof(u16 h) {
    return __uint_as_float(((unsigned)h) << 16);
}

__device__ __forceinline__ void gload16(const u16* g, u16* l) {
    __builtin_amdgcn_global_load_lds(
        (const __attribute__((address_space(1))) unsigned int*)g,
        (__attribute__((address_space(3))) unsigned int*)l, 16, 0, 0);
}

// ---------------- embedding / copies ----------------
__global__ void k_embed(const int* __restrict__ ids, const float* __restrict__ emb,
                        float* __restrict__ out) {
    int row = blockIdx.x;
    int id  = ids[row];
    const f4* src = (const f4*)(emb + (size_t)id * DD);
    f4*       dst = (f4*)(out + (size_t)row * DD);
    for (int i = threadIdx.x; i < DD / 4; i += blockDim.x) dst[i] = src[i];
}

__global__ void k_copy_int(const int* __restrict__ src, int* __restrict__ dst, int n) {
    int i = blockIdx.x * blockDim.x + threadIdx.x;
    if (i < n) dst[i] = src[i];
}

// ---------------- rmsnorm -> bf16 hi/lo planes ----------------
__global__ __launch_bounds__(256) void k_rmsnorm_cvt(const float* __restrict__ x,
                                                     const float* __restrict__ w,
                                                     u16* __restrict__ OH,
                                                     u16* __restrict__ OL) {
    int row = blockIdx.x;
    const float* xr = x + (size_t)row * DD;
    float ss = 0.f;
    for (int i = threadIdx.x; i < DD / 4; i += blockDim.x) {
        f4 v = ((const f4*)xr)[i];
        ss += v.x * v.x + v.y * v.y + v.z * v.z + v.w * v.w;
    }
    for (int o = 32; o > 0; o >>= 1) ss += __shfl_down(ss, o);
    __shared__ float red[4];
    int wid = threadIdx.x >> 6, lane = threadIdx.x & 63;
    if (lane == 0) red[wid] = ss;
    __syncthreads();
    float tot = red[0] + red[1] + red[2] + red[3];
    float inv = 1.0f / sqrtf(tot / (float)DD + 1e-6f);
    for (int i = threadIdx.x; i < DD / 4; i += blockDim.x) {
        f4 v = ((const f4*)xr)[i];
        f4 wv = ((const f4*)w)[i];
        float o[4];
        o[0] = v.x * wv.x * inv; o[1] = v.y * wv.y * inv;
        o[2] = v.z * wv.z * inv; o[3] = v.w * wv.w * inv;
        ushort4 hv, lv;
        u16* hp = (u16*)&hv; u16* lp = (u16*)&lv;
#pragma unroll
        for (int j = 0; j < 4; j++) {
            u16 h = bf16rne(o[j]);
            hp[j] = h;
            lp[j] = bf16rne(o[j] - bf16tof(h));
        }
        *(ushort4*)&OH[(size_t)row * DD + i * 4] = hv;
        *(ushort4*)&OL[(size_t)row * DD + i * 4] = lv;
    }
}

// ---------------- weight transpose+convert: W[K][N] -> planes [n][K] -------
__global__ __launch_bounds__(256) void k_cvt_w(const float* __restrict__ W,
                                               u16* __restrict__ WtH,
                                               u16* __restrict__ WtL,
                                               int K, int N, int nc0, int dn0,
                                               int writeLo) {
    __shared__ float T[64][65];
    int tid = threadIdx.x;
    int n0g = nc0 + blockIdx.x * 64;
    int k0  = blockIdx.y * 64;
#pragma unroll
    for (int it = 0; it < 4; it++) {
        int r = it * 16 + (tid >> 4);
        int c4 = (tid & 15) * 4;
        f4 v = *(const f4*)(W + (size_t)(k0 + r) * N + n0g + c4);
        T[r][c4 + 0] = v.x; T[r][c4 + 1] = v.y;
        T[r][c4 + 2] = v.z; T[r][c4 + 3] = v.w;
    }
    __syncthreads();
    int nl = tid >> 2;
    int ks = (tid & 3) * 16;
    u16 hi[16], lo[16];
#pragma unroll
    for (int j = 0; j < 16; j++) {
        float v = T[ks + j][nl];
        u16 h = bf16rne(v);
        hi[j] = h;
        lo[j] = bf16rne(v - bf16tof(h));
    }
    size_t base = (size_t)(dn0 + blockIdx.x * 64 + nl) * K + k0 + ks;
    *(short8*)&WtH[base]     = *(short8*)&hi[0];
    *(short8*)&WtH[base + 8] = *(short8*)&hi[8];
    if (writeLo) {
        *(short8*)&WtL[base]     = *(short8*)&lo[0];
        *(short8*)&WtL[base + 8] = *(short8*)&lo[8];
    }
}

// ---------------- bf16 MFMA GEMM, m97 structure ----------------
template <int PASSES, int RES, int DUAL>
__global__ __launch_bounds__(256, 2) void k_bgemm(const u16* __restrict__ AH,
                                                  const u16* __restrict__ AL,
                                                  const u16* __restrict__ B1H,
                                                  const u16* __restrict__ B1L,
                                                  const u16* __restrict__ B2H,
                                                  const u16* __restrict__ B2L,
                                                  const float* __restrict__ Rsrc,
                                                  float* __restrict__ C,
                                                  u16* __restrict__ OH,
                                                  u16* __restrict__ OL,
                                                  int M, int ldC, int K) {
    constexpr int NW = DUAL ? 2 : 1;
    __shared__ u16 As[128 * 32];
    __shared__ u16 Bs[NW][128 * 32];
    int tid = threadIdx.x;
    int m0 = blockIdx.y * 128, n0 = blockIdx.x * 128;
    int lane = tid & 63, w = tid >> 6;
    int wm = w >> 1, wn = w & 1;
    int lr = lane & 15, lq = lane >> 4;
    int grow = lane >> 2;
    int gcol = (lane & 3) * 8;

    f32x4 acc[NW][4][4];
#pragma unroll
    for (int u = 0; u < NW; u++)
#pragma unroll
        for (int i = 0; i < 4; i++)
#pragma unroll
            for (int j = 0; j < 4; j++)
#pragma unroll
                for (int r = 0; r < 4; r++) acc[u][i][j][r] = 0.f;

    const int KT = PASSES * K;
    for (int kb = 0; kb < KT; kb += 32) {
        int p  = (PASSES > 1) ? ((kb >= 2 * K) ? 2 : ((kb >= K) ? 1 : 0)) : 0;
        int ks = kb - p * K;
        const u16* Ab = ((p == 2) ? AL  : AH)  + (size_t)(m0 + w * 32) * K + ks;
        const u16* Bb = ((p == 1) ? B1L : B1H) + (size_t)(n0 + w * 32) * K + ks;
        __syncthreads();
        gload16(Ab + (size_t)grow * K + gcol,        &As[w * 1024]);
        gload16(Ab + (size_t)(grow + 16) * K + gcol, &As[w * 1024 + 512]);
        gload16(Bb + (size_t)grow * K + gcol,        &Bs[0][w * 1024]);
        gload16(Bb + (size_t)(grow + 16) * K + gcol, &Bs[0][w * 1024 + 512]);
        if constexpr (DUAL) {
            const u16* B2b = ((p == 1) ? B2L : B2H) + (size_t)(n0 + w * 32) * K + ks;
            gload16(B2b + (size_t)grow * K + gcol,        &Bs[1][w * 1024]);
            gload16(B2b + (size_t)(grow + 16) * K + gcol, &Bs[1][w * 1024 + 512]);
        }
        __syncthreads();
        short8 a[4];
#pragma unroll
        for (int i = 0; i < 4; i++)
            a[i] = *(const short8*)&As[(wm * 64 + i * 16 + lr) * 32 + lq * 8];
#pragma unroll
        for (int u = 0; u < NW; u++) {
#pragma unroll
            for (int j = 0; j < 4; j++) {
                short8 b = *(const short8*)&Bs[u][(wn * 64 + j * 16 + lr) * 32 + lq * 8];
#pragma unroll
                for (int i = 0; i < 4; i++)
                    acc[u][i][j] = __builtin_amdgcn_mfma_f32_16x16x32_bf16(
                        a[i], b, acc[u][i][j], 0, 0, 0);
            }
        }
    }
#pragma unroll
    for (int i = 0; i < 4; i++) {
#pragma unroll
        for (int j = 0; j < 4; j++) {
            int gm = m0 + wm * 64 + i * 16 + lq * 4;
            int gn = n0 + wn * 64 + j * 16 + lr;
#pragma unroll
            for (int r = 0; r < 4; r++) {
                size_t off = (size_t)(gm + r) * ldC + gn;
                if constexpr (DUAL) {
                    float g = acc[0][i][j][r], uu = acc[1][i][j][r];
                    float v = g / (1.0f + expf(-g)) * uu;
                    u16 h = bf16rne(v);
                    OH[off] = h;
                    OL[off] = bf16rne(v - bf16tof(h));
                } else {
                    float v = acc[0][i][j][r];
                    if constexpr (RES) v += Rsrc[off];
                    C[off] = v;
                }
            }
        }
    }
}

// ---------------- RoPE ----------------
__global__ void k_rope_table(float* __restrict__ cosT, float* __restrict__ sinT) {
    int idx = blockIdx.x * blockDim.x + threadIdx.x;
    if (idx >= SSEQ * 64) return;
    int pos = idx >> 6, d = idx & 63;
    float p   = (float)pow(10000.0, (double)d * (1.0 / 64.0));
    float inv = 1.0f / p;
    float ang = (float)pos * inv;
    cosT[idx] = (float)cos((double)ang);
    sinT[idx] = (float)sin((double)ang);
}

// rotates Q (col h*128+d) and K (col 2048+h*128+d) of CQKV[row][ld]
__global__ void k_rope(float* __restrict__ C,
                       const float* __restrict__ cosT, const float* __restrict__ sinT,
                       int s, int ld) {
    int bi = blockIdx.x;
    int h = bi % HH;
    int i = (bi / HH) % s;
    size_t base = (size_t)(bi / HH) * ld + h * DHH;
    int d = threadIdx.x;
    float c  = cosT[i * 64 + d];
    float sn = sinT[i * 64 + d];
    float x1 = C[base + d], x2 = C[base + 64 + d];
    C[base + d]      = x1 * c - x2 * sn;
    C[base + 64 + d] = x1 * sn + x2 * c;
    x1 = C[base + 2048 + d]; x2 = C[base + 2048 + 64 + d];
    C[base + 2048 + d]      = x1 * c - x2 * sn;
    C[base + 2048 + 64 + d] = x1 * sn + x2 * c;
}

// ---------------- Q/K fp32 -> bf16 hi/lo planes (post-rope) ----------------
__global__ __launch_bounds__(256) void k_cvt_qk(const float* __restrict__ C,
                                                u16* __restrict__ QHp, u16* __restrict__ QLp,
                                                u16* __restrict__ KHp, u16* __restrict__ KLp) {
    int row = blockIdx.x;
    int c = threadIdx.x * 8;
#pragma unroll
    for (int sec = 0; sec < 2; sec++) {
        const float* src = C + (size_t)row * 6144 + sec * 2048 + c;
        u16* dh = (sec ? KHp : QHp) + (size_t)row * 2048 + c;
        u16* dl = (sec ? KLp : QLp) + (size_t)row * 2048 + c;
        u16 hbuf[8], lbuf[8];
#pragma unroll
        for (int q = 0; q < 2; q++) {
            f4 v = *(const f4*)(src + q * 4);
            float a[4] = {v.x, v.y, v.z, v.w};
#pragma unroll
            for (int e = 0; e < 4; e++) {
                u16 h = bf16rne(a[e]);
                hbuf[q * 4 + e] = h;
                lbuf[q * 4 + e] = bf16rne(a[e] - bf16tof(h));
            }
        }
        *(short8*)dh = *(short8*)&hbuf[0];
        *(short8*)dl = *(short8*)&lbuf[0];
    }
}

// ---------------- V -> transposed swizzled planes Vt[b*h][128][s] ----------
// granule swizzle within each 32-kv block: data granule g stored at g^(d&3)
__global__ __launch_bounds__(256) void k_cvt_vt(const float* __restrict__ C,
                                                u16* __restrict__ VtH,
                                                u16* __restrict__ VtL, int s) {
    __shared__ float T[64][132];
    int bh = blockIdx.y;
    int h = bh & 15, b = bh >> 4;
    int kv0 = blockIdx.x * 64;
    int t = threadIdx.x;
#pragma unroll
    for (int it = 0; it < 8; it++) {
        int kv = it * 8 + (t >> 5);
        int c4 = (t & 31) * 4;
        f4 v = *(const f4*)(C + (size_t)((size_t)b * s + kv0 + kv) * 6144 + 4096 + h * 128 + c4);
        T[kv][c4 + 0] = v.x; T[kv][c4 + 1] = v.y;
        T[kv][c4 + 2] = v.z; T[kv][c4 + 3] = v.w;
    }
    __syncthreads();
    int d = t >> 1, seg = t & 1;
    size_t base = ((size_t)bh * 128 + d) * s + kv0 + seg * 32;
#pragma unroll
    for (int g = 0; g < 4; g++) {
        u16 h8[8], l8[8];
#pragma unroll
        for (int e = 0; e < 8; e++) {
            float v = T[seg * 32 + g * 8 + e][d];
            u16 hh = bf16rne(v);
            h8[e] = hh;
            l8[e] = bf16rne(v - bf16tof(hh));
        }
        int gp = (g ^ (d & 3)) * 8;
        *(short8*)&VtH[base + gp] = *(short8*)&h8[0];
        *(short8*)&VtL[base + gp] = *(short8*)&l8[0];
    }
}

// ---------------- MFMA flash attention ----------------
// Q-tile 64 (4 waves x 16-row strips), KV-tile 32, 16x16x32 MFMA.
// PASSES=3: bf16x2 (hh, hl, lh) on both QK and PV. PASSES=1: plain bf16.
template <int PASSES>
__global__ __launch_bounds__(256, 2) void k_attn_mfma(
        const u16* __restrict__ QHp, const u16* __restrict__ QLp,
        const u16* __restrict__ KHp, const u16* __restrict__ KLp,
        const u16* __restrict__ VtH, const u16* __restrict__ VtL,
        const int* __restrict__ mask,
        u16* __restrict__ OH, u16* __restrict__ OL, int s) {
    __shared__ u16 SM[21504];
    u16* KsH = SM;              // [4][32][32]
    u16* KsL = SM + 4096;
    u16* VsH = SM + 8192;       // [128][32]
    u16* VsL = SM + 12288;
    int tid = threadIdx.x, lane = tid & 63, w = tid >> 6;
    int lr = lane & 15, lq = lane >> 4;
    int grow = lane >> 2, gcol = (lane & 3) * 8;
    int qt = blockIdx.x, bh = blockIdx.y;
    int h = bh & 15, b = bh >> 4;
    int q0 = qt * 64;
    size_t rb = (size_t)b * s;
    const u16* vtH = VtH + (size_t)bh * 128 * s;
    const u16* vtL = VtL + (size_t)bh * 128 * s;
    u16* PHw = SM + 16384 + w * 1280;   // [16][40] per wave
    u16* PLw = PHw + 640;
    const float scale = 0.08838834764831845f;   // 1/sqrt(128)

    // ---- stage Q, load fragments into registers ----
    short8 qh[4], ql[4];
    {
        const u16* qp = QHp + (rb + q0) * 2048 + h * 128 + w * 32;
#pragma unroll
        for (int it = 0; it < 4; it++)
            gload16(qp + (size_t)(it * 16 + grow) * 2048 + gcol, SM + w * 2048 + it * 512);
        __syncthreads();
#pragma unroll
        for (int ks = 0; ks < 4; ks++)
            qh[ks] = *(const short8*)&SM[ks * 2048 + (w * 16 + lr) * 32 + lq * 8];
        if constexpr (PASSES > 1) {
            __syncthreads();
            const u16* qp2 = QLp + (rb + q0) * 2048 + h * 128 + w * 32;
#pragma unroll
            for (int it = 0; it < 4; it++)
                gload16(qp2 + (size_t)(it * 16 + grow) * 2048 + gcol, SM + w * 2048 + it * 512);
            __syncthreads();
#pragma unroll
            for (int ks = 0; ks < 4; ks++)
                ql[ks] = *(const short8*)&SM[ks * 2048 + (w * 16 + lr) * 32 + lq * 8];
        }
    }

    f32x4 o_acc[8];
#pragma unroll
    for (int j = 0; j < 8; j++)
#pragma unroll
        for (int r = 0; r < 4; r++) o_acc[j][r] = 0.f;
    float m_run[4], l_run[4];
#pragma unroll
    for (int r = 0; r < 4; r++) { m_run[r] = -3.0e38f; l_run[r] = 0.f; }

    int nt = (q0 + 64) >> 5;
    for (int t = 0; t < nt; t++) {
        __syncthreads();
        {   // stage K (kstep w) and V (d rows w*32..+31)
            const u16* kp = KHp + (rb + t * 32) * 2048 + h * 128 + w * 32;
            gload16(kp + (size_t)grow * 2048 + gcol,        KsH + w * 1024);
            gload16(kp + (size_t)(16 + grow) * 2048 + gcol, KsH + w * 1024 + 512);
            const u16* vp = vtH + (size_t)(w * 32) * s + t * 32;
            gload16(vp + (size_t)grow * s + gcol,        VsH + (w * 32) * 32);
            gload16(vp + (size_t)(16 + grow) * s + gcol, VsH + (w * 32 + 16) * 32);
            if constexpr (PASSES > 1) {
                const u16* kp2 = KLp + (rb + t * 32) * 2048 + h * 128 + w * 32;
                gload16(kp2 + (size_t)grow * 2048 + gcol,        KsL + w * 1024);
                gload16(kp2 + (size_t)(16 + grow) * 2048 + gcol, KsL + w * 1024 + 512);
                const u16* vp2 = vtL + (size_t)(w * 32) * s + t * 32;
                gload16(vp2 + (size_t)grow * s + gcol,        VsL + (w * 32) * 32);
                gload16(vp2 + (size_t)(16 + grow) * s + gcol, VsL + (w * 32 + 16) * 32);
            }
        }
        __syncthreads();
        // ---- QK^T ----
        f32x4 sa[2];
#pragma unroll
        for (int j = 0; j < 2; j++)
#pragma unroll
            for (int r = 0; r < 4; r++) sa[j][r] = 0.f;
#pragma unroll
        for (int j = 0; j < 2; j++) {
#pragma unroll
            for (int ks = 0; ks < 4; ks++) {
                short8 kb = *(const short8*)&KsH[ks * 1024 + (j * 16 + lr) * 32 + lq * 8];
                sa[j] = __builtin_amdgcn_mfma_f32_16x16x32_bf16(qh[ks], kb, sa[j], 0, 0, 0);
                if constexpr (PASSES > 1) {
                    short8 kl2 = *(const short8*)&KsL[ks * 1024 + (j * 16 + lr) * 32 + lq * 8];
                    sa[j] = __builtin_amdgcn_mfma_f32_16x16x32_bf16(qh[ks], kl2, sa[j], 0, 0, 0);
                    sa[j] = __builtin_amdgcn_mfma_f32_16x16x32_bf16(ql[ks], kb, sa[j], 0, 0, 0);
                }
            }
        }
        // ---- mask + online softmax (rows owned by (lq,r); reduce over lr) ----
        int mv0 = mask[rb + t * 32 + lr];
        int mv1 = mask[rb + t * 32 + 16 + lr];
        float sclv[4];
#pragma unroll
        for (int r = 0; r < 4; r++) {
            int ig = q0 + w * 16 + lq * 4 + r;
            float v0 = (t * 32 + lr <= ig && mv0 > 0) ? sa[0][r] * scale : -1.0e9f;
            float v1 = (t * 32 + 16 + lr <= ig && mv1 > 0) ? sa[1][r] * scale : -1.0e9f;
            float mx = fmaxf(v0, v1);
            mx = fmaxf(mx, __shfl_xor(mx, 1));
            mx = fmaxf(mx, __shfl_xor(mx, 2));
            mx = fmaxf(mx, __shfl_xor(mx, 4));
            mx = fmaxf(mx, __shfl_xor(mx, 8));
            float mo = m_run[r];
            float mn = fmaxf(mo, mx);
            float p0 = expf(v0 - mn), p1 = expf(v1 - mn);
            float ps = p0 + p1;
            ps += __shfl_xor(ps, 1);
            ps += __shfl_xor(ps, 2);
            ps += __shfl_xor(ps, 4);
            ps += __shfl_xor(ps, 8);
            sclv[r] = expf(mo - mn);
            m_run[r] = mn;
            l_run[r] = l_run[r] * sclv[r] + ps;
            int prow = lq * 4 + r;
            u16 h0 = bf16rne(p0);
            u16 h1 = bf16rne(p1);
            PHw[prow * 40 + lr] = h0;
            PHw[prow * 40 + 16 + lr] = h1;
            if constexpr (PASSES > 1) {
                PLw[prow * 40 + lr] = bf16rne(p0 - bf16tof(h0));
                PLw[prow * 40 + 16 + lr] = bf16rne(p1 - bf16tof(h1));
            }
        }
        // ---- rescale O ----
#pragma unroll
        for (int j = 0; j < 8; j++)
#pragma unroll
            for (int r = 0; r < 4; r++) o_acc[j][r] *= sclv[r];
        // ---- PV ----
        short8 ph = *(const short8*)&PHw[lr * 40 + lq * 8];
        short8 pl;
        if constexpr (PASSES > 1) pl = *(const short8*)&PLw[lr * 40 + lq * 8];
        int gp = (lq ^ (lr & 3)) * 8;
#pragma unroll
        for (int j = 0; j < 8; j++) {
            int vrow = j * 16 + lr;
            short8 vh = *(const short8*)&VsH[vrow * 32 + gp];
            o_acc[j] = __builtin_amdgcn_mfma_f32_16x16x32_bf16(ph, vh, o_acc[j], 0, 0, 0);
            if constexpr (PASSES > 1) {
                short8 vl = *(const short8*)&VsL[vrow * 32 + gp];
                o_acc[j] = __builtin_amdgcn_mfma_f32_16x16x32_bf16(ph, vl, o_acc[j], 0, 0, 0);
                o_acc[j] = __builtin_amdgcn_mfma_f32_16x16x32_bf16(pl, vh, o_acc[j], 0, 0, 0);
            }
        }
    }
    // ---- epilogue: O -> bf16 hi/lo planes ----
#pragma unroll
    for (int r = 0; r < 4; r++) {
        float linv = 1.0f / l_run[r];
        size_t rowoff = (rb + q0 + w * 16 + lq * 4 + r) * 2048 + h * 128 + lr;
#pragma unroll
        for (int j = 0; j < 8; j++) {
            float v = o_acc[j][r] * linv;
            u16 hh = bf16rne(v);
            OH[rowoff + j * 16] = hh;
            OL[rowoff + j * 16] = bf16rne(v - bf16tof(hh));
        }
    }
}

// ---------------- fp32 flash attention (tier D fallback) ----------------
__global__ __launch_bounds__(256, 2) void k_attn_f32(const float* __restrict__ Q,
                                                     const float* __restrict__ K,
                                                     const float* __restrict__ V,
                                                     const int* __restrict__ mask,
                                                     u16* __restrict__ OH,
                                                     u16* __restrict__ OL, int s, int ld) {
    int qt = blockIdx.x, bh = blockIdx.y;
    int h = bh & (HH - 1), b = bh >> 4;
    __shared__ float Qs[64][132];
    __shared__ float Ks[32 * 128];
    __shared__ float Vs[32][132];
    __shared__ float Ps[64][36];
    __shared__ float mrow[64], lrow[64];
    int tid = threadIdx.x;
    int tx = tid & 15, ty = tid >> 4;

#pragma unroll
    for (int p = 0; p < 2; p++) {
        int r = p * 32 + (tid >> 3);
        int kb = (tid & 7) * 4;
        const float* src = Q + (size_t)(b * s + qt * 64 + r) * ld + h * DHH;
#pragma unroll
        for (int q = 0; q < 4; q++)
            *(f4*)&Qs[r][kb + 32 * q] = *(const f4*)(src + kb + 32 * q);
    }
    if (tid < 64) { mrow[tid] = -3.0e38f; lrow[tid] = 0.f; }

    float acc[4][8];
#pragma unroll
    for (int i = 0; i < 4; i++)
#pragma unroll
        for (int c = 0; c < 8; c++) acc[i][c] = 0.f;
    const float scale = 0.08838834764831845f;

    int ktmax = 2 * (qt + 1);
    for (int kt = 0; kt < ktmax; kt++) {
        __syncthreads();
#pragma unroll
        for (int p = 0; p < 4; p++) {
            int c = p * 8 + (tid >> 5);
            int kk = (tid & 31) * 4;
            size_t g = (size_t)(b * s + kt * 32 + c) * ld + h * DHH + kk;
            f4 kv = *(const f4*)(K + g);
            int ch = (kk >> 2) ^ (c >> 1);
            *(f4*)&Ks[c * 128 + ch * 4] = kv;
            *(f4*)&Vs[c][kk] = *(const f4*)(V + g);
        }
        __syncthreads();
        float sv[4][2];
#pragma unroll
        for (int i = 0; i < 4; i++) { sv[i][0] = 0.f; sv[i][1] = 0.f; }
        for (int kk = 0; kk < 128; kk += 4) {
            f4 qv[4];
#pragma unroll
            for (int i = 0; i < 4; i++) qv[i] = *(const f4*)&Qs[ty * 4 + i][kk];
#pragma unroll
            for (int j = 0; j < 2; j++) {
                int c = tx * 2 + j;
                int ch = (kk >> 2) ^ (c >> 1);
                f4 kv = *(const f4*)&Ks[c * 128 + ch * 4];
#pragma unroll
                for (int i = 0; i < 4; i++)
                    sv[i][j] += qv[i].x * kv.x + qv[i].y * kv.y +
                                qv[i].z * kv.z + qv[i].w * kv.w;
            }
        }
        float scl[4];
#pragma unroll
        for (int i = 0; i < 4; i++) {
            int r = ty * 4 + i;
            int igl = qt * 64 + r;
#pragma unroll
            for (int j = 0; j < 2; j++) {
                int jg = kt * 32 + tx * 2 + j;
                bool ok = (jg <= igl) && (mask[b * s + jg] > 0);
                sv[i][j] = ok ? sv[i][j] * scale : -1.0e9f;
            }
            float rmax = fmaxf(sv[i][0], sv[i][1]);
            rmax = fmaxf(rmax, __shfl_xor(rmax, 1));
            rmax = fmaxf(rmax, __shfl_xor(rmax, 2));
            rmax = fmaxf(rmax, __shfl_xor(rmax, 4));
            rmax = fmaxf(rmax, __shfl_xor(rmax, 8));
            float mold = mrow[r];
            float mnew = fmaxf(mold, rmax);
            float p0 = expf(sv[i][0] - mnew);
            float p1 = expf(sv[i][1] - mnew);
            float ps = p0 + p1;
            ps += __shfl_xor(ps, 1);
            ps += __shfl_xor(ps, 2);
            ps += __shfl_xor(ps, 4);
            ps += __shfl_xor(ps, 8);
            scl[i] = expf(mold - mnew);
            if (tx == 0) { mrow[r] = mnew; lrow[r] = lrow[r] * scl[i] + ps; }
            float2 pw; pw.x = p0; pw.y = p1;
            *(float2*)&Ps[r][tx * 2] = pw;
        }
        __syncthreads();
#pragma unroll
        for (int i = 0; i < 4; i++) {
            float sc = scl[i];
#pragma unroll
            for (int c = 0; c < 8; c++) acc[i][c] *= sc;
        }
        for (int jj = 0; jj < 32; jj += 4) {
            f4 pv[4];
#pragma unroll
            for (int i = 0; i < 4; i++) pv[i] = *(const f4*)&Ps[ty * 4 + i][jj];
#pragma unroll
            for (int j2 = 0; j2 < 4; j2++) {
                f4 va = *(const f4*)&Vs[jj + j2][tx * 4];
                f4 vb = *(const f4*)&Vs[jj + j2][64 + tx * 4];
#pragma unroll
                for (int i = 0; i < 4; i++) {
                    float p = (&pv[i].x)[j2];
                    acc[i][0] += p * va.x; acc[i][1] += p * va.y;
                    acc[i][2] += p * va.z; acc[i][3] += p * va.w;
                    acc[i][4] += p * vb.x; acc[i][5] += p * vb.y;
                    acc[i][6] += p * vb.z; acc[i][7] += p * vb.w;
                }
            }
        }
    }
    __syncthreads();
#pragma unroll
    for (int i = 0; i < 4; i++) {
        int r = ty * 4 + i;
        float linv = 1.0f / lrow[r];
        size_t ob = (size_t)(b * s + qt * 64 + r) * DD + h * DHH;
        ushort4 h1, l1, h2, l2;
        u16 *h1p = (u16*)&h1, *l1p = (u16*)&l1, *h2p = (u16*)&h2, *l2p = (u16*)&l2;
#pragma unroll
        for (int c = 0; c < 4; c++) {
            float v = acc[i][c] * linv;
            u16 hh = bf16rne(v);
            h1p[c] = hh; l1p[c] = bf16rne(v - bf16tof(hh));
            float v2 = acc[i][c + 4] * linv;
            u16 hh2 = bf16rne(v2);
            h2p[c] = hh2; l2p[c] = bf16rne(v2 - bf16tof(hh2));
        }
        *(ushort4*)&OH[ob + tx * 4] = h1;
        *(ushort4*)&OL[ob + tx * 4] = l1;
        *(ushort4*)&OH[ob + 64 + tx * 4] = h2;
        *(ushort4*)&OL[ob + 64 + tx * 4] = l2;
    }
}

// ---------------- prune scoring / selection ----------------
__global__ __launch_bounds__(256) void k_score(const float* __restrict__ Hb,
                                               const float* __restrict__ srow,
                                               float* __restrict__ sc) {
    int row = blockIdx.x;
    const float* xr = Hb + (size_t)row * DD;
    float ss = 0.f;
    for (int i = threadIdx.x; i < DD / 4; i += blockDim.x) {
        f4 a = ((const f4*)xr)[i];
        f4 w = ((const f4*)srow)[i];
        ss += a.x * w.x + a.y * w.y + a.z * w.z + a.w * w.w;
    }
    for (int o = 32; o > 0; o >>= 1) ss += __shfl_down(ss, o);
    __shared__ float red[4];
    int wid = threadIdx.x >> 6, lane = threadIdx.x & 63;
    if (lane == 0) red[wid] = ss;
    __syncthreads();
    if (threadIdx.x == 0) sc[row] = red[0] + red[1] + red[2] + red[3];
}

__global__ __launch_bounds__(256) void k_rank(const float* __restrict__ sc,
                                              int* __restrict__ flg, int s, int kk) {
    int b = blockIdx.x / s, i = blockIdx.x % s;
    const float* scb = sc + (size_t)b * s;
    float vi = scb[i];
    int cnt = 0;
    for (int j = threadIdx.x; j < s; j += 256) {
        float vj = scb[j];
        if (vj > vi || (vj == vi && j < i)) cnt++;
    }
    for (int o = 32; o > 0; o >>= 1) cnt += __shfl_down(cnt, o);
    __shared__ int red[4];
    int wid = threadIdx.x >> 6, lane = threadIdx.x & 63;
    if (lane == 0) red[wid] = cnt;
    __syncthreads();
    if (threadIdx.x == 0) flg[b * s + i] = ((red[0] + red[1] + red[2] + red[3]) < kk) ? 1 : 0;
}

__global__ void k_compact(const int* __restrict__ flg, int* __restrict__ idx, int s, int kk) {
    int b = blockIdx.x;
    if (threadIdx.x == 0) {
        int p = 0;
        for (int i = 0; i < s; i++)
            if (flg[b * s + i]) idx[b * kk + (p++)] = i;
    }
}

__global__ void k_gather(const float* __restrict__ Hin, const int* __restrict__ idx,
                         float* __restrict__ Hout, int s, int kk) {
    int row = blockIdx.x;
    int b = row / kk, p = row % kk;
    int i = idx[b * kk + p];
    const f4* src = (const f4*)(Hin + (size_t)(b * s + i) * DD);
    f4* dst = (f4*)(Hout + (size_t)row * DD);
    for (int t = threadIdx.x; t < DD / 4; t += blockDim.x) dst[t] = src[t];
}

__global__ void k_gather_mask(const int* __restrict__ Min, const int* __restrict__ idx,
                              int* __restrict__ Mout, int s, int kk) {
    int t = blockIdx.x * blockDim.x + threadIdx.x;
    if (t < BBATCH * kk) {
        int b = t / kk, p = t % kk;
        Mout[t] = Min[b * s + idx[b * kk + p]];
    }
}

// ---------------------------------------------------------------------------
extern "C" void kernel_launch(void* const* d_in, const int* in_sizes, int n_in,
                              void* d_out, int out_size, void* d_ws, size_t ws_size,
                              hipStream_t stream) {
    const int*   input_ids = (const int*)d_in[0];
    const int*   attn_mask = (const int*)d_in[1];
    const float* embed     = (const float*)d_in[2];
    const float* wq        = (const float*)d_in[3];
    const float* wk        = (const float*)d_in[4];
    const float* wv        = (const float*)d_in[5];
    const float* wo        = (const float*)d_in[6];
    const float* wg        = (const float*)d_in[7];
    const float* wu        = (const float*)d_in[8];
    const float* wd        = (const float*)d_in[9];
    const float* ln1       = (const float*)d_in[10];
    const float* ln2       = (const float*)d_in[11];
    const float* lnf       = (const float*)d_in[12];
    const float* lm_head   = (const float*)d_in[13];
    const float* scorer    = (const float*)d_in[14];

    float* ws = (float*)d_ws;
    const size_t R = (size_t)BBATCH * SSEQ * DD;        // 8,388,608 floats
    const size_t MISC_FLOATS = 2 * SSEQ * 64 + 5 * (size_t)BBATCH * SSEQ + 1024;
    const size_t NEED_A = (14 * R + MISC_FLOATS) * 4;   // ~471 MB
    const bool bigws = (ws_size >= NEED_A);

    float* H0   = ws;
    float* H1   = ws + R;
    float* CQKV = ws + 2 * R;                           // [4096][6144] fp32
    u16*   AH   = (u16*)(ws + 5 * R);                   // [4096][2048] planes
    u16*   AL   = AH + (size_t)4096 * DD;

    // tier A: attention-phase planes live in the (then-idle) FF region 6R..9R
    u16* QHp = (u16*)(ws + 6 * R);
    u16* QLp = QHp + (size_t)4096 * DD;
    u16* KHp = (u16*)(ws + 7 * R);
    u16* KLp = KHp + (size_t)4096 * DD;
    u16* VtH = (u16*)(ws + 8 * R);
    u16* VtL = VtH + (size_t)4096 * DD;
    // tier A MLP regions
    u16* FH  = (u16*)(ws + 6 * R);                      // [4096][8192]
    u16* FL  = (u16*)(ws + 8 * R);
    u16* WH1 = (u16*)(ws + 10 * R);
    u16* WL1 = WH1 + (size_t)FFF * DD;
    u16* WH2 = (u16*)(ws + 12 * R);
    u16* WL2 = WH2 + (size_t)FFF * DD;
    u16* WDH = (u16*)(ws + 10 * R);
    u16* WDL = WDH + (size_t)DD * FFF;
    u16* WQKVH = (u16*)(ws + 10 * R);                   // [6144][2048]
    u16* WQKVL = WQKVH + (size_t)6144 * DD;

    // tier D regions
    u16* cWgH = (u16*)CQKV;
    u16* cWgL = cWgH + (size_t)2048 * DD;
    u16* cWuH = cWgL + (size_t)2048 * DD;
    u16* cWuL = cWuH + (size_t)2048 * DD;
    u16* cFH  = (u16*)(ws + 3 * R);
    u16* cFL  = cFH + (size_t)4096 * 2048;
    u16* cWdH = (u16*)(ws + 4 * R);
    u16* cWdL = cWdH + (size_t)2048 * DD;

    float* miscB = ws + (bigws ? 14 * R : 6 * R);
    float* COS = miscB;
    float* SIN = COS + SSEQ * 64;
    float* SC  = SIN + SSEQ * 64;
    int*   FLG = (int*)(SC + (size_t)BBATCH * SSEQ);
    int*   IDX = FLG + BBATCH * SSEQ;
    int*   M0  = IDX + BBATCH * SSEQ;
    int*   M1  = M0 + BBATCH * SSEQ;

    k_rope_table<<<(SSEQ * 64 + 255) / 256, 256, 0, stream>>>(COS, SIN);
    k_embed<<<BBATCH * SSEQ, 256, 0, stream>>>(input_ids, embed, H0);
    k_copy_int<<<(BBATCH * SSEQ + 255) / 256, 256, 0, stream>>>(attn_mask, M0, BBATCH * SSEQ);

    float* Hc = H0; float* Nc = H1;
    int*   Mc = M0; int*   Mt = M1;
    int s = SSEQ;

    for (int l = 0; l < LLAYERS; l++) {
        if (l == 1 || l == 2) {
            int pi = l - 1;
            int kk = s / 2;
            k_score<<<BBATCH * s, 256, 0, stream>>>(Hc, scorer + (size_t)pi * 2 * DD, SC);
            k_rank<<<BBATCH * s, 256, 0, stream>>>(SC, FLG, s, kk);
            k_compact<<<BBATCH, 64, 0, stream>>>(FLG, IDX, s, kk);
            k_gather<<<BBATCH * kk, 256, 0, stream>>>(Hc, IDX, Nc, s, kk);
            k_gather_mask<<<(BBATCH * kk + 255) / 256, 256, 0, stream>>>(Mc, IDX, Mt, s, kk);
            { float* t = Hc; Hc = Nc; Nc = t; }
            { int* t = Mc; Mc = Mt; Mt = t; }
            s = kk;
        }
        int rows = BBATCH * s;
        const bool hiP = (l < 2);
        const int wlo = hiP ? 1 : 0;
        const float* Wq = wq + (size_t)l * DD * DD;
        const float* Wk = wk + (size_t)l * DD * DD;
        const float* Wv = wv + (size_t)l * DD * DD;
        const float* Wo = wo + (size_t)l * DD * DD;
        const float* Wg = wg + (size_t)l * DD * FFF;
        const float* Wu = wu + (size_t)l * DD * FFF;
        const float* Wd = wd + (size_t)l * FFF * DD;
        const float* L1 = ln1 + (size_t)l * DD;
        const float* L2 = ln2 + (size_t)l * DD;

        dim3 gWd(DD / 64, DD / 64);

        // ---- QKV projection (fused) ----
        k_rmsnorm_cvt<<<rows, 256, 0, stream>>>(Hc, L1, AH, AL);
        if (bigws) {
            k_cvt_w<<<gWd, 256, 0, stream>>>(Wq, WQKVH, WQKVL, DD, DD, 0, 0, wlo);
            k_cvt_w<<<gWd, 256, 0, stream>>>(Wk, WQKVH, WQKVL, DD, DD, 0, 2048, wlo);
            k_cvt_w<<<gWd, 256, 0, stream>>>(Wv, WQKVH, WQKVL, DD, DD, 0, 4096, wlo);
            dim3 gQKV(6144 / 128, rows / 128);
            if (hiP) k_bgemm<3,0,0><<<gQKV,256,0,stream>>>(AH,AL,WQKVH,WQKVL,nullptr,nullptr,nullptr,CQKV,nullptr,nullptr,rows,6144,DD);
            else     k_bgemm<1,0,0><<<gQKV,256,0,stream>>>(AH,AL,WQKVH,WQKVL,nullptr,nullptr,nullptr,CQKV,nullptr,nullptr,rows,6144,DD);
        } else {
            u16* WtH = (u16*)Nc;
            u16* WtL = WtH + (size_t)DD * DD;
            dim3 gG(DD / 128, rows / 128);
            const float* Wqkv[3] = {Wq, Wk, Wv};
            for (int q3 = 0; q3 < 3; q3++) {
                k_cvt_w<<<gWd, 256, 0, stream>>>(Wqkv[q3], WtH, WtL, DD, DD, 0, 0, wlo);
                float* Cb = CQKV + q3 * 2048;
                if (hiP) k_bgemm<3,0,0><<<gG,256,0,stream>>>(AH,AL,WtH,WtL,nullptr,nullptr,nullptr,Cb,nullptr,nullptr,rows,6144,DD);
                else     k_bgemm<1,0,0><<<gG,256,0,stream>>>(AH,AL,WtH,WtL,nullptr,nullptr,nullptr,Cb,nullptr,nullptr,rows,6144,DD);
            }
        }
        k_rope<<<rows * HH, 64, 0, stream>>>(CQKV, COS, SIN, s, 6144);

        // ---- attention ----
        if (bigws) {
            k_cvt_qk<<<rows, 256, 0, stream>>>(CQKV, QHp, QLp, KHp, KLp);
            k_cvt_vt<<<dim3(s / 64, BBATCH * HH), 256, 0, stream>>>(CQKV, VtH, VtL, s);
            if (hiP) k_attn_mfma<3><<<dim3(s / 64, BBATCH * HH), 256, 0, stream>>>(
                         QHp, QLp, KHp, KLp, VtH, VtL, Mc, AH, AL, s);
            else     k_attn_mfma<1><<<dim3(s / 64, BBATCH * HH), 256, 0, stream>>>(
                         QHp, QLp, KHp, KLp, VtH, VtL, Mc, AH, AL, s);
        } else {
            k_attn_f32<<<dim3(s / 64, BBATCH * HH), 256, 0, stream>>>(
                CQKV, CQKV + 2048, CQKV + 4096, Mc, AH, AL, s, 6144);
        }

        // ---- wo projection + residual ----
        {
            u16* WtH = bigws ? WQKVH : (u16*)Nc;
            u16* WtL = bigws ? (WQKVH + (size_t)DD * DD) : ((u16*)Nc + (size_t)DD * DD);
            k_cvt_w<<<gWd, 256, 0, stream>>>(Wo, WtH, WtL, DD, DD, 0, 0, wlo);
            dim3 gG(DD / 128, rows / 128);
            if (hiP) k_bgemm<3,1,0><<<gG,256,0,stream>>>(AH,AL,WtH,WtL,nullptr,nullptr,Hc,Hc,nullptr,nullptr,rows,DD,DD);
            else     k_bgemm<1,1,0><<<gG,256,0,stream>>>(AH,AL,WtH,WtL,nullptr,nullptr,Hc,Hc,nullptr,nullptr,rows,DD,DD);
        }

        // ---- MLP ----
        k_rmsnorm_cvt<<<rows, 256, 0, stream>>>(Hc, L2, AH, AL);
        if (bigws) {
            k_cvt_w<<<dim3(FFF / 64, DD / 64), 256, 0, stream>>>(Wg, WH1, WL1, DD, FFF, 0, 0, wlo);
            k_cvt_w<<<dim3(FFF / 64, DD / 64), 256, 0, stream>>>(Wu, WH2, WL2, DD, FFF, 0, 0, wlo);
            if (hiP) k_bgemm<3,0,1><<<dim3(FFF/128, rows/128),256,0,stream>>>(AH,AL,WH1,WL1,WH2,WL2,nullptr,nullptr,FH,FL,rows,FFF,DD);
            else     k_bgemm<1,0,1><<<dim3(FFF/128, rows/128),256,0,stream>>>(AH,AL,WH1,WL1,WH2,WL2,nullptr,nullptr,FH,FL,rows,FFF,DD);
            k_cvt_w<<<dim3(DD / 64, FFF / 64), 256, 0, stream>>>(Wd, WDH, WDL, FFF, DD, 0, 0, wlo);
            if (hiP) k_bgemm<3,1,0><<<dim3(DD/128, rows/128),256,0,stream>>>(FH,FL,WDH,WDL,nullptr,nullptr,Hc,Hc,nullptr,nullptr,rows,DD,FFF);
            else     k_bgemm<1,1,0><<<dim3(DD/128, rows/128),256,0,stream>>>(FH,FL,WDH,WDL,nullptr,nullptr,Hc,Hc,nullptr,nullptr,rows,DD,FFF);
        } else {
            for (int ffc = 0; ffc < FFF; ffc += 2048) {
                k_cvt_w<<<dim3(2048 / 64, DD / 64), 256, 0, stream>>>(Wg, cWgH, cWgL, DD, FFF, ffc, 0, wlo);
                k_cvt_w<<<dim3(2048 / 64, DD / 64), 256, 0, stream>>>(Wu, cWuH, cWuL, DD, FFF, ffc, 0, wlo);
                if (hiP) k_bgemm<3,0,1><<<dim3(16, rows/128),256,0,stream>>>(AH,AL,cWgH,cWgL,cWuH,cWuL,nullptr,nullptr,cFH,cFL,rows,2048,DD);
                else     k_bgemm<1,0,1><<<dim3(16, rows/128),256,0,stream>>>(AH,AL,cWgH,cWgL,cWuH,cWuL,nullptr,nullptr,cFH,cFL,rows,2048,DD);
                k_cvt_w<<<dim3(DD / 64, 2048 / 64), 256, 0, stream>>>(Wd + (size_t)ffc * DD, cWdH, cWdL, 2048, DD, 0, 0, wlo);
                if (hiP) k_bgemm<3,1,0><<<dim3(DD/128, rows/128),256,0,stream>>>(cFH,cFL,cWdH,cWdL,nullptr,nullptr,Hc,Hc,nullptr,nullptr,rows,DD,2048);
                else     k_bgemm<1,1,0><<<dim3(DD/128, rows/128),256,0,stream>>>(cFH,cFL,cWdH,cWdL,nullptr,nullptr,Hc,Hc,nullptr,nullptr,rows,DD,2048);
            }
        }
    }

    // ---- final rmsnorm + lm_head ----
    int rows = BBATCH * s;   // 1024
    u16* AHf = (u16*)Nc;
    u16* ALf = AHf + (size_t)rows * DD;
    u16* LmH = bigws ? (u16*)(ws + 6 * R) : (u16*)CQKV;
    k_rmsnorm_cvt<<<rows, 256, 0, stream>>>(Hc, lnf, AHf, ALf);
    k_cvt_w<<<dim3(VV / 64, DD / 64), 256, 0, stream>>>(lm_head, LmH, LmH, DD, VV, 0, 0, 0);
    k_bgemm<1,0,0><<<dim3(VV / 128, rows / 128), 256, 0, stream>>>(
        AHf, ALf, LmH, LmH, nullptr, nullptr, nullptr, (float*)d_out,
        nullptr, nullptr, rows, VV, DD);
}